// Round 6
// baseline (1827.062 us; speedup 1.0000x reference)
//
#include <hip/hip_runtime.h>
#include <hip/hip_bf16.h>
#include <cmath>
#include <complex>
#include <vector>
#include <cstring>
#include <cstdint>

// ---------------------------------------------------------------------------
// ShieldingT2Model: f32, round 6 — fused kernel, slim LDS, register phase-5.
// B=16384, NS=64, NK=32, NL=16, HM=256, HC=128, out = (B,5) f32.
//
// r3 fused 143KB LDS (1 blk/CU)          : 1994 us, VALU 15%
// r4 ws-split                            : 3750 us (k_tp2 scratch-spill GBs)
// r5 fused 73.7KB LDS (2 blk/CU)         : 1760 us, VALU 25%, occ 47%
// r6: phase-5 keeps y2 in registers (same (bl,xw) map as producer), y2L
//     eliminated -> ~40.4KB LDS -> 3-4 blk/CU; w022 pre-transposed for
//     contiguous streams; packed pair table.
//
// ws (~2 MB): mixed @0 | w202T @327680 | wsym @393216 | w022T @1458176
// C222 sign: majority-positive canonicalization, then flipped (r2/r3 A/B).
// ---------------------------------------------------------------------------

#define C222_FLIP -1.0f

#define MIX_WS_OFF   0
#define W202T_OFF    327680
#define WSYM_OFF     393216
#define W022T_OFF    1458176

struct Coefs {
  float c222[125];   // full (2,2,2) real wigner-3j, [i][j][k]
  float d022[5];     // diag of C022[0,:,:]
  float d202[5];     // diag of C202[:,0,:]
  float d220[5];     // diag of C220[:,:,0]
  float a0, a2, b2;
};

#define FMA8(acc, wa, wb, sv) do { \
  acc[0] = fmaf((wa).x, (sv), acc[0]); \
  acc[1] = fmaf((wa).y, (sv), acc[1]); \
  acc[2] = fmaf((wa).z, (sv), acc[2]); \
  acc[3] = fmaf((wa).w, (sv), acc[3]); \
  acc[4] = fmaf((wb).x, (sv), acc[4]); \
  acc[5] = fmaf((wb).y, (sv), acc[5]); \
  acc[6] = fmaf((wb).z, (sv), acc[6]); \
  acc[7] = fmaf((wb).w, (sv), acc[7]); \
} while (0)

#define FMA4(acc, wa, sv) do { \
  acc[0] = fmaf((wa).x, (sv), acc[0]); \
  acc[1] = fmaf((wa).y, (sv), acc[1]); \
  acc[2] = fmaf((wa).z, (sv), acc[2]); \
  acc[3] = fmaf((wa).w, (sv), acc[3]); \
} while (0)

__device__ __forceinline__ float act_silu(float x) {
  return 1.679f * x / (1.0f + expf(-x));   // SILU_NORM * silu(x)
}

// ---------------------------------------------------------------------------
// K1: MLP -> weights -> mixed.  32 b per wg, 256 threads. (proven)
// ---------------------------------------------------------------------------
__global__ __launch_bounds__(256) void k_prep(
    const float* __restrict__ s, const float* __restrict__ t2s,
    const float* __restrict__ w1, const float* __restrict__ w2,
    const float* __restrict__ w3, const float* __restrict__ gthr,
    float* __restrict__ mixed_ws)
{
  __shared__ float sT[64][36];    // [k][b], padded
  __shared__ float hT[256][36];   // [c][b], holds h1 then h2

  const int tid = threadIdx.x;
  const int b0  = blockIdx.x * 32;

  #pragma unroll
  for (int i = 0; i < 8; i++) {
    int flat = tid + i * 256;
    int bl = flat >> 6, k = flat & 63;
    sT[k][bl] = s[(size_t)(b0 + bl) * 64 + k];
  }
  __syncthreads();

  const int cg = tid & 31, bg = tid >> 5;
  const int c0 = cg * 8, bb0 = bg * 4;

  float acc[4][8];
  #pragma unroll
  for (int j = 0; j < 4; j++)
    #pragma unroll
    for (int i = 0; i < 8; i++) acc[j][i] = 0.f;

  for (int k = 0; k < 64; k++) {
    float4 bv = *(const float4*)&sT[k][bb0];
    float4 wa = *(const float4*)&w1[k * 256 + c0];
    float4 wb = *(const float4*)&w1[k * 256 + c0 + 4];
    const float bvv[4] = {bv.x, bv.y, bv.z, bv.w};
    #pragma unroll
    for (int j = 0; j < 4; j++) { FMA8(acc[j], wa, wb, bvv[j]); }
  }
  #pragma unroll
  for (int j = 0; j < 4; j++)
    #pragma unroll
    for (int i = 0; i < 8; i++)
      hT[c0 + i][bb0 + j] = act_silu(acc[j][i] * 0.125f);
  __syncthreads();

  float acc2[4][8];
  #pragma unroll
  for (int j = 0; j < 4; j++)
    #pragma unroll
    for (int i = 0; i < 8; i++) acc2[j][i] = 0.f;

  for (int k = 0; k < 256; k++) {
    float4 bv = *(const float4*)&hT[k][bb0];
    float4 wa = *(const float4*)&w2[k * 256 + c0];
    float4 wb = *(const float4*)&w2[k * 256 + c0 + 4];
    const float bvv[4] = {bv.x, bv.y, bv.z, bv.w};
    #pragma unroll
    for (int j = 0; j < 4; j++) { FMA8(acc2[j], wa, wb, bvv[j]); }
  }
  __syncthreads();
  #pragma unroll
  for (int j = 0; j < 4; j++)
    #pragma unroll
    for (int i = 0; i < 8; i++)
      hT[c0 + i][bb0 + j] = act_silu(acc2[j][i] * 0.0625f);
  __syncthreads();

  const int jj  = tid & 31;
  const int blg = tid >> 5;
  float acc3[4] = {0.f, 0.f, 0.f, 0.f};
  for (int k = 0; k < 256; k++) {
    float wv  = w3[k * 32 + jj];
    float4 hv = *(const float4*)&hT[k][blg * 4];
    acc3[0] = fmaf(hv.x, wv, acc3[0]);
    acc3[1] = fmaf(hv.y, wv, acc3[1]);
    acc3[2] = fmaf(hv.z, wv, acc3[2]);
    acc3[3] = fmaf(hv.w, wv, acc3[3]);
  }
  const float thrv = gthr[jj];
  #pragma unroll
  for (int r = 0; r < 4; r++) {
    int bl = blg * 4 + r;
    int b  = b0 + bl;
    float rel = acc3[r] * 0.0625f;
    const float* tp = t2s + (size_t)(b * 32 + jj) * 5;
    float tv0 = tp[0], tv1 = tp[1], tv2 = tp[2], tv3 = tp[3], tv4 = tp[4];
    float mag  = sqrtf(tv0*tv0 + tv1*tv1 + tv2*tv2 + tv3*tv3 + tv4*tv4);
    float gate = mag / (mag + thrv);
    float w = rel * gate * 0.17677669529663687f;  // 1/sqrt(32)
    float pm0 = w*tv0, pm1 = w*tv1, pm2 = w*tv2, pm3 = w*tv3, pm4 = w*tv4;
    #pragma unroll
    for (int off = 16; off >= 1; off >>= 1) {
      pm0 += __shfl_xor(pm0, off);
      pm1 += __shfl_xor(pm1, off);
      pm2 += __shfl_xor(pm2, off);
      pm3 += __shfl_xor(pm3, off);
      pm4 += __shfl_xor(pm4, off);
    }
    if (jj == 0) {
      float* mp = mixed_ws + (size_t)b * 5;
      mp[0] = pm0; mp[1] = pm1; mp[2] = pm2; mp[3] = pm3; mp[4] = pm4;
    }
  }
}

// ---------------------------------------------------------------------------
// K2: merged weight prep.
//  blocks 0..63   : symmetrize w000 -> packed upper-tri wsym (2080x128)
//  blocks 64..127 : transpose tp2_w202 (128x128) -> w202T
//  blocks 128..255: transpose w022 [u64][v16][w128] -> w022T [v][u][w]
// ---------------------------------------------------------------------------
__global__ __launch_bounds__(256) void k_wprep(
    const float* __restrict__ w000, float* __restrict__ wsym,
    const float* __restrict__ w2202, float* __restrict__ w202T,
    const float* __restrict__ w022, float* __restrict__ w022T)
{
  const int tid = threadIdx.x;
  const int blk = blockIdx.x;
  if (blk < 64) {
    int u = blk;
    int base = u * 64 - (u * (u - 1)) / 2;
    int n = (64 - u) * 128;
    for (int idx = tid; idx < n; idx += 256) {
      int t = idx >> 7, wc = idx & 127;
      int v = u + t;
      float val = w000[(size_t)(u * 64 + v) * 128 + wc];
      if (v > u) val += w000[(size_t)(v * 64 + u) * 128 + wc];
      wsym[(size_t)(base + t) * 128 + wc] = val;
    }
  } else if (blk < 128) {
    int idx = (blk - 64) * 256 + tid;  // 16384
    int u = idx >> 7, v = idx & 127;
    w202T[v * 128 + u] = w2202[u * 128 + v];
  } else {
    int e0 = (blk - 128) * 1024;       // 128 blocks x 1024 = 131072
    #pragma unroll
    for (int i = 0; i < 4; i++) {
      int e = e0 + i * 256 + tid;
      int w = e & 127, r = e >> 7;     // r = u*16+v
      int u = r >> 4, v = r & 15;
      w022T[(size_t)(v * 64 + u) * 128 + w] = w022[e];
    }
  }
}

// ---------------------------------------------------------------------------
// K3: fused heavy kernel. 16 b per block, 1024 blocks, 512 threads.
// LDS ~40.4 KB -> 3-4 blocks/CU (24-32 waves/CU).
// thread map everywhere: bl = tid>>5 (batch 0..15), xw = tid&31, w0 = xw*4.
// Each thread owns w-channels [w0..w0+3]; y2 fragment stays in registers.
// ---------------------------------------------------------------------------
__global__ __launch_bounds__(512, 4) void k_fused(
    const float* __restrict__ s, const float* __restrict__ t2s,
    const float* __restrict__ mixed_ws,
    const float* __restrict__ wsym,  const float* __restrict__ w220,
    const float* __restrict__ w022T, const float* __restrict__ w202,
    const float* __restrict__ w222,
    const float* __restrict__ w2022, const float* __restrict__ w202T,
    const float* __restrict__ w2222,
    const float* __restrict__ csc, float* __restrict__ out, Coefs cf)
{
  __shared__ float sL[16][65];                    // 4160 B
  __shared__ float tL[16][16][5];                 // 5120 B
  __shared__ float y0L[16][128];                  // 8192 B
  __shared__ float cL222[125];                    //  500 B
  __shared__ float corrAcc[16][5];                //  320 B
  __shared__ float pPL[16][25];                   // 1600 B
  __shared__ unsigned short p16[2080];            // 4160 B
  __shared__ __align__(16) char uni[16384];       // union (time-disjoint):
  //   y220 : grA  = float[16*256]        @ uni
  //   tp222: GLb  = float[16][25]        @ uni ; QLb = float[16][16][5] @+1664
  //   ph5  : y2iL = float[16][128]       @ uni
  float* grA = (float*)uni;
  float (*GLb)[25]    = (float(*)[25])uni;
  float (*QLb)[16][5] = (float(*)[16][5])(uni + 1664);
  float (*y2iL)[128]  = (float(*)[128])uni;
  // total ~40.4 KB

  const int tid = threadIdx.x;
  const int b0  = blockIdx.x * 16;

  float dk022[5], dk202[5], dk220[5];
  #pragma unroll
  for (int k = 0; k < 5; k++) {
    dk022[k] = cf.d022[k]; dk202[k] = cf.d202[k]; dk220[k] = cf.d220[k];
  }

  // ---- stage ----
  if (tid == 0) {
    #pragma unroll
    for (int i = 0; i < 125; i++) cL222[i] = cf.c222[i];
  }
  for (int idx = tid; idx < 16 * 64; idx += 512) {
    int bl = idx >> 6, k = idx & 63;
    sL[bl][k] = s[(size_t)(b0 + bl) * 64 + k];
  }
  for (int idx = tid; idx < 16 * 80; idx += 512) {
    int bl = idx / 80, rem = idx - bl * 80;
    int u = rem / 5, m = rem - u * 5;
    int b = b0 + bl;
    float v;
    if (u < 15) v = t2s[(size_t)(b * 32 + u) * 5 + m];
    else {
      v = 0.f;
      for (int kk = 0; kk < 32; kk++) v += t2s[(size_t)(b * 32 + kk) * 5 + m];
    }
    tL[bl][u][m] = v;
  }
  if (tid < 64) {  // packed pair table p -> (u<<8)|v
    int u = tid;
    int base = u * 64 - (u * (u - 1)) / 2;
    for (int t = 0; t < 64 - u; t++)
      p16[base + t] = (unsigned short)((u << 8) | (u + t));
  }
  __syncthreads();

  // gram for all (u,v) -> grA
  for (int idx = tid; idx < 16 * 256; idx += 512) {
    int bb = idx >> 8, r = idx & 255;
    int u = r >> 4, v = r & 15;
    float g = 0.f;
    #pragma unroll
    for (int m = 0; m < 5; m++)
      g = fmaf(dk220[m] * tL[bb][u][m], tL[bb][v][m], g);
    grA[bb * 256 + r] = g;
  }
  __syncthreads();

  const int xw = tid & 31;
  const int bl = tid >> 5;
  const int w0 = xw * 4;

  // ---- y000: flat pair loop ----
  float y0acc[4] = {0.f, 0.f, 0.f, 0.f};
  #pragma unroll 8
  for (int p = 0; p < 2080; p++) {
    int uv = p16[p];
    float prod = sL[bl][uv >> 8] * sL[bl][uv & 255];
    float4 w4 = *(const float4*)(wsym + (size_t)p * 128 + w0);
    FMA4(y0acc, w4, prod);
  }
  // ---- y220: flat 256 loop ----
  #pragma unroll 8
  for (int q = 0; q < 256; q++) {
    float gv = grA[bl * 256 + q];
    float4 w4 = *(const float4*)(w220 + (size_t)q * 128 + w0);
    FMA4(y0acc, w4, gv);
  }
  #pragma unroll
  for (int wi = 0; wi < 4; wi++) y0L[bl][w0 + wi] = cf.a0 * y0acc[wi];
  __syncthreads();  // grA dead; all y220 reads done

  // ---- y2 (accumulated in registers) ----
  float y2acc[5][4];
  #pragma unroll
  for (int k = 0; k < 5; k++)
    #pragma unroll
    for (int wi = 0; wi < 4; wi++) y2acc[k][wi] = 0.f;

  // tp022 (w022T: [v][u][w], contiguous stream)
  for (int v = 0; v < 16; v++) {
    float a4[4] = {0.f, 0.f, 0.f, 0.f};
    #pragma unroll 8
    for (int u = 0; u < 64; u++) {
      float su = sL[bl][u];
      float4 w4 = *(const float4*)(w022T + (size_t)(v * 64 + u) * 128 + w0);
      FMA4(a4, w4, su);
    }
    #pragma unroll
    for (int k = 0; k < 5; k++) {
      float fk = dk022[k] * tL[bl][v][k];
      #pragma unroll
      for (int wi = 0; wi < 4; wi++) y2acc[k][wi] = fmaf(fk, a4[wi], y2acc[k][wi]);
    }
  }
  // tp202 ([u][v][w], already contiguous in v)
  for (int u = 0; u < 16; u++) {
    float a4[4] = {0.f, 0.f, 0.f, 0.f};
    #pragma unroll 8
    for (int v = 0; v < 64; v++) {
      float sv = sL[bl][v];
      float4 w4 = *(const float4*)(w202 + (size_t)(u * 64 + v) * 128 + w0);
      FMA4(a4, w4, sv);
    }
    #pragma unroll
    for (int k = 0; k < 5; k++) {
      float fk = dk202[k] * tL[bl][u][k];
      #pragma unroll
      for (int wi = 0; wi < 4; wi++) y2acc[k][wi] = fmaf(fk, a4[wi], y2acc[k][wi]);
    }
  }
  // tp222
  for (int u = 0; u < 16; u++) {
    if (tid < 400) {
      int bb = tid / 25, jk = tid - bb * 25;
      float g = 0.f;
      #pragma unroll
      for (int ii = 0; ii < 5; ii++)
        g = fmaf(cL222[ii * 25 + jk], tL[bb][u][ii], g);
      GLb[bb][jk] = g;
    }
    __syncthreads();
    for (int idx = tid; idx < 1280; idx += 512) {
      int bb = idx / 80, rem = idx - bb * 80;
      int vv = rem / 5, kk = rem - vv * 5;
      float q = 0.f;
      #pragma unroll
      for (int jj = 0; jj < 5; jj++)
        q = fmaf(GLb[bb][jj * 5 + kk], tL[bb][vv][jj], q);
      QLb[bb][vv][kk] = q;
    }
    __syncthreads();
    #pragma unroll 4
    for (int v = 0; v < 16; v++) {
      float4 w4 = *(const float4*)(w222 + (size_t)(u * 16 + v) * 128 + w0);
      #pragma unroll
      for (int k = 0; k < 5; k++) {
        float qv = QLb[bl][v][k];
        FMA4(y2acc[k], w4, qv);
      }
    }
    __syncthreads();   // QLb reads done
  }
  // scale y2 in registers
  #pragma unroll
  for (int k = 0; k < 5; k++)
    #pragma unroll
    for (int wi = 0; wi < 4; wi++) y2acc[k][wi] *= cf.a2;

  // ================= phase 5: tp2, register-resident y2 =================
  // 022 path: gv[v]=sum_u W2022[u,v] y0[u]; corr += d022[k]*sum_v gv*y2[k,v]
  {
    float gvr[4] = {0.f, 0.f, 0.f, 0.f};
    #pragma unroll 8
    for (int u = 0; u < 128; u++) {
      float y0u = y0L[bl][u];
      float4 w4 = *(const float4*)(w2022 + (size_t)u * 128 + w0);
      FMA4(gvr, w4, y0u);
    }
    #pragma unroll
    for (int k = 0; k < 5; k++) {
      float p = gvr[0] * y2acc[k][0] + gvr[1] * y2acc[k][1]
              + gvr[2] * y2acc[k][2] + gvr[3] * y2acc[k][3];
      p += __shfl_xor(p, 16); p += __shfl_xor(p, 8); p += __shfl_xor(p, 4);
      p += __shfl_xor(p, 2);  p += __shfl_xor(p, 1);
      if (xw == 0) corrAcc[bl][k] = dk022[k] * p;
    }
  }
  // 202 path: hv[u]=sum_v W2202[u,v] y0[v] (via w202T); corr += d202[k]*...
  {
    float hvr[4] = {0.f, 0.f, 0.f, 0.f};
    #pragma unroll 8
    for (int v = 0; v < 128; v++) {
      float y0v = y0L[bl][v];
      float4 w4 = *(const float4*)(w202T + (size_t)v * 128 + w0);
      FMA4(hvr, w4, y0v);
    }
    #pragma unroll
    for (int k = 0; k < 5; k++) {
      float p = hvr[0] * y2acc[k][0] + hvr[1] * y2acc[k][1]
              + hvr[2] * y2acc[k][2] + hvr[3] * y2acc[k][3];
      p += __shfl_xor(p, 16); p += __shfl_xor(p, 8); p += __shfl_xor(p, 4);
      p += __shfl_xor(p, 2);  p += __shfl_xor(p, 1);
      if (xw == 0) corrAcc[bl][k] += dk202[k] * p;   // same unique writer
    }
  }
  // 222 path: Z_i[v]=sum_u W2222[u,v] y2[i,u]; P[i][j]=sum_v Z_i[v] y2[j,v]
  for (int i = 0; i < 5; i++) {
    {  // stage component i of y2 (all u) into y2iL
      float4 o;
      o.x = y2acc[i][0]; o.y = y2acc[i][1]; o.z = y2acc[i][2]; o.w = y2acc[i][3];
      *(float4*)(&y2iL[bl][w0]) = o;
    }
    __syncthreads();
    float zr[4] = {0.f, 0.f, 0.f, 0.f};
    #pragma unroll 8
    for (int u = 0; u < 128; u++) {
      float yu = y2iL[bl][u];
      float4 w4 = *(const float4*)(w2222 + (size_t)u * 128 + w0);
      FMA4(zr, w4, yu);
    }
    #pragma unroll
    for (int j = 0; j < 5; j++) {
      float p = zr[0] * y2acc[j][0] + zr[1] * y2acc[j][1]
              + zr[2] * y2acc[j][2] + zr[3] * y2acc[j][3];
      p += __shfl_xor(p, 16); p += __shfl_xor(p, 8); p += __shfl_xor(p, 4);
      p += __shfl_xor(p, 2);  p += __shfl_xor(p, 1);
      if (xw == 0) pPL[bl][i * 5 + j] = p;
    }
    __syncthreads();   // y2iL reads done before next i's overwrite
  }

  // ---- epilogue ----
  if (tid < 80) {
    int bb = tid / 5, k = tid - bb * 5;
    float c2 = 0.f;
    #pragma unroll
    for (int ii = 0; ii < 5; ii++)
      #pragma unroll
      for (int jj = 0; jj < 5; jj++)
        c2 = fmaf(cL222[ii * 25 + jj * 5 + k], pPL[bb][ii * 5 + jj], c2);
    float tot = corrAcc[bb][k] + c2;
    int b = b0 + bb;
    out[(size_t)b * 5 + k] = mixed_ws[(size_t)b * 5 + k] + csc[0] * cf.b2 * tot;
  }
}

// ---------------------------------------------------------------------------
// Host: replicate reference's wigner-3j computation (RREF null space).
// ---------------------------------------------------------------------------
namespace {

using cplx = std::complex<double>;

static void su2_gen(int l, std::vector<cplx>& Jx, std::vector<cplx>& Jy,
                    std::vector<cplx>& Jz) {
  int d = 2 * l + 1;
  Jx.assign((size_t)d * d, cplx(0, 0));
  Jy.assign((size_t)d * d, cplx(0, 0));
  Jz.assign((size_t)d * d, cplx(0, 0));
  for (int a = 0; a < d; a++) Jz[(size_t)a * d + a] = cplx(a - l, 0);
  for (int r = 1; r < d; r++) {
    double m = (r - 1) - l;
    double v = std::sqrt(l * (l + 1.0) - m * (m + 1.0));
    Jx[(size_t)r * d + (r - 1)] += cplx(v / 2, 0);
    Jx[(size_t)(r - 1) * d + r] += cplx(v / 2, 0);
    Jy[(size_t)r * d + (r - 1)] += cplx(0, -v / 2);
    Jy[(size_t)(r - 1) * d + r] += cplx(0, v / 2);
  }
}

static void real_basis(int l, std::vector<cplx>& U) {
  int d = 2 * l + 1;
  U.assign((size_t)d * d, cplx(0, 0));
  U[(size_t)l * d + l] = cplx(1, 0);
  double is2 = 1.0 / std::sqrt(2.0);
  for (int m = 1; m <= l; m++) {
    double sgn = (m % 2 == 0) ? 1.0 : -1.0;
    U[(size_t)(l + m) * d + (l + m)] = cplx(sgn * is2, 0);
    U[(size_t)(l + m) * d + (l - m)] = cplx(is2, 0);
    U[(size_t)(l - m) * d + (l - m)] = cplx(0, is2);
    U[(size_t)(l - m) * d + (l + m)] = cplx(0, -sgn * is2);
  }
}

static void real_gens(int l, std::vector<double> G[3]) {
  int d = 2 * l + 1;
  if (l == 0) { for (int a = 0; a < 3; a++) G[a].assign(1, 0.0); return; }
  std::vector<cplx> J[3];
  su2_gen(l, J[0], J[1], J[2]);
  std::vector<cplx> U;
  real_basis(l, U);
  for (int a = 0; a < 3; a++) {
    std::vector<cplx> T((size_t)d * d, cplx(0, 0));
    for (int i = 0; i < d; i++)
      for (int k = 0; k < d; k++) {
        cplx s(0, 0);
        for (int j = 0; j < d; j++)
          s += U[(size_t)i * d + j] * (cplx(0, -1) * J[a][(size_t)j * d + k]);
        T[(size_t)i * d + k] = s;
      }
    G[a].assign((size_t)d * d, 0.0);
    for (int i = 0; i < d; i++)
      for (int k = 0; k < d; k++) {
        cplx s(0, 0);
        for (int j = 0; j < d; j++)
          s += T[(size_t)i * d + j] * std::conj(U[(size_t)k * d + j]);
        G[a][(size_t)i * d + k] = s.real();
      }
  }
}

static void w3j_host(int l1, int l2, int l3, float* out) {
  int d1 = 2 * l1 + 1, d2 = 2 * l2 + 1, d3 = 2 * l3 + 1;
  int D = d1 * d2 * d3;
  std::vector<double> G1[3], G2[3], G3[3];
  real_gens(l1, G1); real_gens(l2, G2); real_gens(l3, G3);
  int R = 3 * D;
  std::vector<double> M((size_t)R * D, 0.0);
  for (int a = 0; a < 3; a++) {
    double* Ma = &M[(size_t)a * D * D];
    for (int i1 = 0; i1 < d1; i1++)
      for (int j1 = 0; j1 < d1; j1++) {
        double g = G1[a][(size_t)i1 * d1 + j1];
        if (g == 0.0) continue;
        for (int i2 = 0; i2 < d2; i2++)
          for (int i3 = 0; i3 < d3; i3++)
            Ma[(size_t)((i1 * d2 + i2) * d3 + i3) * D + ((j1 * d2 + i2) * d3 + i3)] += g;
      }
    for (int i2 = 0; i2 < d2; i2++)
      for (int j2 = 0; j2 < d2; j2++) {
        double g = G2[a][(size_t)i2 * d2 + j2];
        if (g == 0.0) continue;
        for (int i1 = 0; i1 < d1; i1++)
          for (int i3 = 0; i3 < d3; i3++)
            Ma[(size_t)((i1 * d2 + i2) * d3 + i3) * D + ((i1 * d2 + j2) * d3 + i3)] += g;
      }
    for (int i3 = 0; i3 < d3; i3++)
      for (int j3 = 0; j3 < d3; j3++) {
        double g = G3[a][(size_t)i3 * d3 + j3];
        if (g == 0.0) continue;
        for (int i1 = 0; i1 < d1; i1++)
          for (int i2 = 0; i2 < d2; i2++)
            Ma[(size_t)((i1 * d2 + i2) * d3 + i3) * D + ((i1 * d2 + i2) * d3 + j3)] += g;
      }
  }
  std::vector<int> pivcol;
  int rank = 0;
  for (int col = 0; col < D && rank < R; col++) {
    int pr = -1; double pv = 1e-9;
    for (int r = rank; r < R; r++) {
      double av = std::fabs(M[(size_t)r * D + col]);
      if (av > pv) { pv = av; pr = r; }
    }
    if (pr < 0) continue;
    if (pr != rank)
      for (int c = 0; c < D; c++) std::swap(M[(size_t)pr * D + c], M[(size_t)rank * D + c]);
    double inv = 1.0 / M[(size_t)rank * D + col];
    for (int c = 0; c < D; c++) M[(size_t)rank * D + c] *= inv;
    for (int r = 0; r < R; r++) {
      if (r == rank) continue;
      double f = M[(size_t)r * D + col];
      if (f != 0.0)
        for (int c = 0; c < D; c++) M[(size_t)r * D + c] -= f * M[(size_t)rank * D + c];
    }
    pivcol.push_back(col);
    rank++;
  }
  std::vector<char> isp(D, 0);
  for (int c : pivcol) isp[c] = 1;
  int fc = 0;
  for (int c = 0; c < D; c++) if (!isp[c]) { fc = c; break; }
  std::vector<double> x(D, 0.0);
  x[fc] = 1.0;
  for (int r = 0; r < rank; r++) x[pivcol[r]] = -M[(size_t)r * D + fc];
  double n = 0;
  for (double v : x) n += v * v;
  n = std::sqrt(n);
  for (int c = 0; c < D; c++) x[c] /= n;
  double best = 0;
  for (int c = 0; c < D; c++) { double av = std::fabs(x[c]); if (av > best) best = av; }
  double ssum = 0;
  for (int c = 0; c < D; c++) {
    double av = std::fabs(x[c]);
    if (av >= best * 0.999) ssum += (x[c] >= 0 ? 1.0 : -1.0);
  }
  double sgn = (ssum >= 0) ? 1.0 : -1.0;
  for (int c = 0; c < D; c++) out[c] = (float)(x[c] * sgn);
}

}  // namespace

// ---------------------------------------------------------------------------
extern "C" void kernel_launch(void* const* d_in, const int* in_sizes, int n_in,
                              void* d_out, int out_size, void* d_ws, size_t ws_size,
                              hipStream_t stream)
{
  (void)in_sizes; (void)n_in; (void)out_size; (void)ws_size;

  const float* s     = (const float*)d_in[0];
  const float* t2s   = (const float*)d_in[1];
  const float* w1    = (const float*)d_in[2];
  const float* w2    = (const float*)d_in[3];
  const float* w3    = (const float*)d_in[4];
  const float* gthr  = (const float*)d_in[5];
  const float* w000  = (const float*)d_in[6];
  const float* w220  = (const float*)d_in[7];
  const float* w022  = (const float*)d_in[8];
  const float* w202  = (const float*)d_in[9];
  const float* w222  = (const float*)d_in[10];
  const float* w2022 = (const float*)d_in[11];
  const float* w2202 = (const float*)d_in[12];
  const float* w2222 = (const float*)d_in[13];
  const float* csc   = (const float*)d_in[14];
  float* out = (float*)d_out;

  char* ws = (char*)d_ws;
  float* mixed_ws = (float*)(ws + MIX_WS_OFF);
  float* w202T    = (float*)(ws + W202T_OFF);
  float* wsym     = (float*)(ws + WSYM_OFF);
  float* w022T    = (float*)(ws + W022T_OFF);

  Coefs cf;
  {
    float c000v[1], c022v[25], c202v[25], c220v[25];
    w3j_host(0, 0, 0, c000v);
    w3j_host(0, 2, 2, c022v);
    w3j_host(2, 0, 2, c202v);
    w3j_host(2, 2, 0, c220v);
    w3j_host(2, 2, 2, cf.c222);
    for (int i = 0; i < 125; i++) cf.c222[i] *= C222_FLIP;
    for (int k = 0; k < 5; k++) {
      cf.d022[k] = c022v[k * 5 + k];
      cf.d202[k] = c202v[k * 5 + k];
      cf.d220[k] = c220v[k * 5 + k];
    }
    (void)c000v;
    cf.a0 = (float)std::sqrt(1.0 / (64.0 * 64.0 + 16.0 * 16.0));
    cf.a2 = (float)std::sqrt(5.0 / (2.0 * 64.0 * 16.0 + 16.0 * 16.0));
    cf.b2 = (float)std::sqrt(5.0 / (3.0 * 128.0 * 128.0));
  }

  hipLaunchKernelGGL(k_prep, dim3(512), dim3(256), 0, stream,
                     s, t2s, w1, w2, w3, gthr, mixed_ws);
  hipLaunchKernelGGL(k_wprep, dim3(256), dim3(256), 0, stream,
                     w000, wsym, w2202, w202T, w022, w022T);
  hipLaunchKernelGGL(k_fused, dim3(1024), dim3(512), 0, stream,
                     s, t2s, mixed_ws, wsym, w220, w022T, w202, w222,
                     w2022, w202T, w2222, csc, out, cf);
}

// Round 7
// 849.215 us; speedup vs baseline: 2.1515x; 2.1515x over previous
//
#include <hip/hip_runtime.h>
#include <hip/hip_bf16.h>
#include <cmath>
#include <complex>
#include <vector>
#include <cstring>
#include <cstdint>

// ---------------------------------------------------------------------------
// ShieldingT2Model: f32, round 7 — fused kernel + 2-batch register reuse.
// B=16384, NS=64, NK=32, NL=16, HM=256, HC=128, out = (B,5) f32.
//
// r3 fused 143KB (1 blk/CU)     : 1994 us, VALU 15%
// r4 ws-split                   : 3750 us (scratch-spill GBs)
// r5 fused 73.7KB (2 blk/CU)    : 1760 us, VALU 25%, occ 47%
// r6 slim 40.4KB                : 1827 us, VALU 20%, occ 46%  <- NOT occupancy
//    bound; cache-BW bound (each weight float4 feeds 1 batch = 0.5 FLOP/B).
// r7: each thread owns TWO batches (bA=2g, bB=2g+1); every weight float4
//     loaded once, used twice -> VMEM instructions/bytes halve. B_blk=32,
//     512 blocks, 512 threads, ~74KB LDS (2 blk/CU, same measured occ).
//
// ws (~2 MB): mixed @0 | w202T @327680 | wsym @393216 | w022T @1458176
// C222 sign: majority-positive canonicalization, then flipped (r2/r3 A/B).
// ---------------------------------------------------------------------------

#define C222_FLIP -1.0f

#define MIX_WS_OFF   0
#define W202T_OFF    327680
#define WSYM_OFF     393216
#define W022T_OFF    1458176

struct Coefs {
  float c222[125];   // full (2,2,2) real wigner-3j, [i][j][k]
  float d022[5];     // diag of C022[0,:,:]
  float d202[5];     // diag of C202[:,0,:]
  float d220[5];     // diag of C220[:,:,0]
  float a0, a2, b2;
};

#define FMA8(acc, wa, wb, sv) do { \
  acc[0] = fmaf((wa).x, (sv), acc[0]); \
  acc[1] = fmaf((wa).y, (sv), acc[1]); \
  acc[2] = fmaf((wa).z, (sv), acc[2]); \
  acc[3] = fmaf((wa).w, (sv), acc[3]); \
  acc[4] = fmaf((wb).x, (sv), acc[4]); \
  acc[5] = fmaf((wb).y, (sv), acc[5]); \
  acc[6] = fmaf((wb).z, (sv), acc[6]); \
  acc[7] = fmaf((wb).w, (sv), acc[7]); \
} while (0)

#define FMA4(acc, wa, sv) do { \
  acc[0] = fmaf((wa).x, (sv), acc[0]); \
  acc[1] = fmaf((wa).y, (sv), acc[1]); \
  acc[2] = fmaf((wa).z, (sv), acc[2]); \
  acc[3] = fmaf((wa).w, (sv), acc[3]); \
} while (0)

__device__ __forceinline__ float act_silu(float x) {
  return 1.679f * x / (1.0f + expf(-x));   // SILU_NORM * silu(x)
}

// ---------------------------------------------------------------------------
// K1: MLP -> weights -> mixed.  32 b per wg, 256 threads. (proven)
// ---------------------------------------------------------------------------
__global__ __launch_bounds__(256) void k_prep(
    const float* __restrict__ s, const float* __restrict__ t2s,
    const float* __restrict__ w1, const float* __restrict__ w2,
    const float* __restrict__ w3, const float* __restrict__ gthr,
    float* __restrict__ mixed_ws)
{
  __shared__ float sT[64][36];    // [k][b], padded
  __shared__ float hT[256][36];   // [c][b], holds h1 then h2

  const int tid = threadIdx.x;
  const int b0  = blockIdx.x * 32;

  #pragma unroll
  for (int i = 0; i < 8; i++) {
    int flat = tid + i * 256;
    int bl = flat >> 6, k = flat & 63;
    sT[k][bl] = s[(size_t)(b0 + bl) * 64 + k];
  }
  __syncthreads();

  const int cg = tid & 31, bg = tid >> 5;
  const int c0 = cg * 8, bb0 = bg * 4;

  float acc[4][8];
  #pragma unroll
  for (int j = 0; j < 4; j++)
    #pragma unroll
    for (int i = 0; i < 8; i++) acc[j][i] = 0.f;

  for (int k = 0; k < 64; k++) {
    float4 bv = *(const float4*)&sT[k][bb0];
    float4 wa = *(const float4*)&w1[k * 256 + c0];
    float4 wb = *(const float4*)&w1[k * 256 + c0 + 4];
    const float bvv[4] = {bv.x, bv.y, bv.z, bv.w};
    #pragma unroll
    for (int j = 0; j < 4; j++) { FMA8(acc[j], wa, wb, bvv[j]); }
  }
  #pragma unroll
  for (int j = 0; j < 4; j++)
    #pragma unroll
    for (int i = 0; i < 8; i++)
      hT[c0 + i][bb0 + j] = act_silu(acc[j][i] * 0.125f);
  __syncthreads();

  float acc2[4][8];
  #pragma unroll
  for (int j = 0; j < 4; j++)
    #pragma unroll
    for (int i = 0; i < 8; i++) acc2[j][i] = 0.f;

  for (int k = 0; k < 256; k++) {
    float4 bv = *(const float4*)&hT[k][bb0];
    float4 wa = *(const float4*)&w2[k * 256 + c0];
    float4 wb = *(const float4*)&w2[k * 256 + c0 + 4];
    const float bvv[4] = {bv.x, bv.y, bv.z, bv.w};
    #pragma unroll
    for (int j = 0; j < 4; j++) { FMA8(acc2[j], wa, wb, bvv[j]); }
  }
  __syncthreads();
  #pragma unroll
  for (int j = 0; j < 4; j++)
    #pragma unroll
    for (int i = 0; i < 8; i++)
      hT[c0 + i][bb0 + j] = act_silu(acc2[j][i] * 0.0625f);
  __syncthreads();

  const int jj  = tid & 31;
  const int blg = tid >> 5;
  float acc3[4] = {0.f, 0.f, 0.f, 0.f};
  for (int k = 0; k < 256; k++) {
    float wv  = w3[k * 32 + jj];
    float4 hv = *(const float4*)&hT[k][blg * 4];
    acc3[0] = fmaf(hv.x, wv, acc3[0]);
    acc3[1] = fmaf(hv.y, wv, acc3[1]);
    acc3[2] = fmaf(hv.z, wv, acc3[2]);
    acc3[3] = fmaf(hv.w, wv, acc3[3]);
  }
  const float thrv = gthr[jj];
  #pragma unroll
  for (int r = 0; r < 4; r++) {
    int bl = blg * 4 + r;
    int b  = b0 + bl;
    float rel = acc3[r] * 0.0625f;
    const float* tp = t2s + (size_t)(b * 32 + jj) * 5;
    float tv0 = tp[0], tv1 = tp[1], tv2 = tp[2], tv3 = tp[3], tv4 = tp[4];
    float mag  = sqrtf(tv0*tv0 + tv1*tv1 + tv2*tv2 + tv3*tv3 + tv4*tv4);
    float gate = mag / (mag + thrv);
    float w = rel * gate * 0.17677669529663687f;  // 1/sqrt(32)
    float pm0 = w*tv0, pm1 = w*tv1, pm2 = w*tv2, pm3 = w*tv3, pm4 = w*tv4;
    #pragma unroll
    for (int off = 16; off >= 1; off >>= 1) {
      pm0 += __shfl_xor(pm0, off);
      pm1 += __shfl_xor(pm1, off);
      pm2 += __shfl_xor(pm2, off);
      pm3 += __shfl_xor(pm3, off);
      pm4 += __shfl_xor(pm4, off);
    }
    if (jj == 0) {
      float* mp = mixed_ws + (size_t)b * 5;
      mp[0] = pm0; mp[1] = pm1; mp[2] = pm2; mp[3] = pm3; mp[4] = pm4;
    }
  }
}

// ---------------------------------------------------------------------------
// K2: merged weight prep (unchanged from r6).
// ---------------------------------------------------------------------------
__global__ __launch_bounds__(256) void k_wprep(
    const float* __restrict__ w000, float* __restrict__ wsym,
    const float* __restrict__ w2202, float* __restrict__ w202T,
    const float* __restrict__ w022, float* __restrict__ w022T)
{
  const int tid = threadIdx.x;
  const int blk = blockIdx.x;
  if (blk < 64) {
    int u = blk;
    int base = u * 64 - (u * (u - 1)) / 2;
    int n = (64 - u) * 128;
    for (int idx = tid; idx < n; idx += 256) {
      int t = idx >> 7, wc = idx & 127;
      int v = u + t;
      float val = w000[(size_t)(u * 64 + v) * 128 + wc];
      if (v > u) val += w000[(size_t)(v * 64 + u) * 128 + wc];
      wsym[(size_t)(base + t) * 128 + wc] = val;
    }
  } else if (blk < 128) {
    int idx = (blk - 64) * 256 + tid;  // 16384
    int u = idx >> 7, v = idx & 127;
    w202T[v * 128 + u] = w2202[u * 128 + v];
  } else {
    int e0 = (blk - 128) * 1024;       // 128 blocks x 1024 = 131072
    #pragma unroll
    for (int i = 0; i < 4; i++) {
      int e = e0 + i * 256 + tid;
      int w = e & 127, r = e >> 7;     // r = u*16+v
      int u = r >> 4, v = r & 15;
      w022T[(size_t)(v * 64 + u) * 128 + w] = w022[e];
    }
  }
}

// ---------------------------------------------------------------------------
// K3: fused heavy kernel. 32 b per block, 512 blocks, 512 threads, ~74KB LDS.
// thread map: xw = tid&31 (channel quad w0=xw*4), g = tid>>5 (0..15),
// batches bA=2g, bB=2g+1. Every weight float4 is loaded ONCE and applied to
// both batches (2x FLOP/byte vs r6).
// ---------------------------------------------------------------------------
__global__ __launch_bounds__(512, 4) void k_fused(
    const float* __restrict__ s, const float* __restrict__ t2s,
    const float* __restrict__ mixed_ws,
    const float* __restrict__ wsym,  const float* __restrict__ w220,
    const float* __restrict__ w022T, const float* __restrict__ w202,
    const float* __restrict__ w222,
    const float* __restrict__ w2022, const float* __restrict__ w202T,
    const float* __restrict__ w2222,
    const float* __restrict__ csc, float* __restrict__ out, Coefs cf)
{
  __shared__ float sL[32][65];                    //  8320 B
  __shared__ float tL[32][16][5];                 // 10240 B
  __shared__ float y0L[32][128];                  // 16384 B
  __shared__ float cL222[125];                    //   500 B
  __shared__ float corrAcc[32][5];                //   640 B
  __shared__ float pPL[32][25];                   //  3200 B
  __shared__ unsigned short p16[2080];            //  4160 B
  __shared__ __align__(16) char uni[32768];       // union (time-disjoint):
  //   y220 : grA  = float[32*256]  (32768 B) @ uni
  //   tp222: GLb  = float[32][25]  (3200 B)  @ uni ; QLb = float[32][16][5] @+3200
  //   ph5  : y2iL = float[32][128] (16384 B) @ uni
  float* grA = (float*)uni;
  float (*GLb)[25]    = (float(*)[25])uni;
  float (*QLb)[16][5] = (float(*)[16][5])(uni + 3200);
  float (*y2iL)[128]  = (float(*)[128])uni;
  // total ~74.4 KB -> 2 blocks/CU

  const int tid = threadIdx.x;
  const int b0  = blockIdx.x * 32;

  float dk022[5], dk202[5], dk220[5];
  #pragma unroll
  for (int k = 0; k < 5; k++) {
    dk022[k] = cf.d022[k]; dk202[k] = cf.d202[k]; dk220[k] = cf.d220[k];
  }

  // ---- stage ----
  if (tid == 0) {
    #pragma unroll
    for (int i = 0; i < 125; i++) cL222[i] = cf.c222[i];
  }
  for (int idx = tid; idx < 32 * 64; idx += 512) {
    int bl = idx >> 6, k = idx & 63;
    sL[bl][k] = s[(size_t)(b0 + bl) * 64 + k];
  }
  for (int idx = tid; idx < 32 * 80; idx += 512) {
    int bl = idx / 80, rem = idx - bl * 80;
    int u = rem / 5, m = rem - u * 5;
    int b = b0 + bl;
    float v;
    if (u < 15) v = t2s[(size_t)(b * 32 + u) * 5 + m];
    else {
      v = 0.f;
      for (int kk = 0; kk < 32; kk++) v += t2s[(size_t)(b * 32 + kk) * 5 + m];
    }
    tL[bl][u][m] = v;
  }
  if (tid < 64) {  // packed pair table p -> (u<<8)|v
    int u = tid;
    int base = u * 64 - (u * (u - 1)) / 2;
    for (int t = 0; t < 64 - u; t++)
      p16[base + t] = (unsigned short)((u << 8) | (u + t));
  }
  __syncthreads();

  // gram for all (u,v) -> grA
  for (int idx = tid; idx < 32 * 256; idx += 512) {
    int bb = idx >> 8, r = idx & 255;
    int u = r >> 4, v = r & 15;
    float g = 0.f;
    #pragma unroll
    for (int m = 0; m < 5; m++)
      g = fmaf(dk220[m] * tL[bb][u][m], tL[bb][v][m], g);
    grA[bb * 256 + r] = g;
  }
  __syncthreads();

  const int xw = tid & 31;
  const int g  = tid >> 5;
  const int bA = 2 * g, bB = 2 * g + 1;
  const int w0 = xw * 4;

  // ---- y000: flat pair loop, weight reused for 2 batches ----
  float y0a[2][4] = {{0.f,0.f,0.f,0.f},{0.f,0.f,0.f,0.f}};
  #pragma unroll 8
  for (int p = 0; p < 2080; p++) {
    int uv = p16[p];
    int u = uv >> 8, v = uv & 255;
    float pa = sL[bA][u] * sL[bA][v];
    float pb = sL[bB][u] * sL[bB][v];
    float4 w4 = *(const float4*)(wsym + (size_t)p * 128 + w0);
    FMA4(y0a[0], w4, pa);
    FMA4(y0a[1], w4, pb);
  }
  // ---- y220 ----
  #pragma unroll 8
  for (int q = 0; q < 256; q++) {
    float ga = grA[bA * 256 + q];
    float gb = grA[bB * 256 + q];
    float4 w4 = *(const float4*)(w220 + (size_t)q * 128 + w0);
    FMA4(y0a[0], w4, ga);
    FMA4(y0a[1], w4, gb);
  }
  #pragma unroll
  for (int wi = 0; wi < 4; wi++) {
    y0L[bA][w0 + wi] = cf.a0 * y0a[0][wi];
    y0L[bB][w0 + wi] = cf.a0 * y0a[1][wi];
  }
  __syncthreads();  // grA dead

  // ---- y2 (registers, both batches) ----
  float y2acc[5][2][4];
  #pragma unroll
  for (int k = 0; k < 5; k++)
    #pragma unroll
    for (int r = 0; r < 2; r++)
      #pragma unroll
      for (int wi = 0; wi < 4; wi++) y2acc[k][r][wi] = 0.f;

  // tp022 (w022T: [v][u][w] contiguous)
  for (int v = 0; v < 16; v++) {
    float a4[2][4] = {{0.f,0.f,0.f,0.f},{0.f,0.f,0.f,0.f}};
    #pragma unroll 8
    for (int u = 0; u < 64; u++) {
      float4 w4 = *(const float4*)(w022T + (size_t)(v * 64 + u) * 128 + w0);
      FMA4(a4[0], w4, sL[bA][u]);
      FMA4(a4[1], w4, sL[bB][u]);
    }
    #pragma unroll
    for (int k = 0; k < 5; k++) {
      float fa = dk022[k] * tL[bA][v][k];
      float fb = dk022[k] * tL[bB][v][k];
      #pragma unroll
      for (int wi = 0; wi < 4; wi++) {
        y2acc[k][0][wi] = fmaf(fa, a4[0][wi], y2acc[k][0][wi]);
        y2acc[k][1][wi] = fmaf(fb, a4[1][wi], y2acc[k][1][wi]);
      }
    }
  }
  // tp202
  for (int u = 0; u < 16; u++) {
    float a4[2][4] = {{0.f,0.f,0.f,0.f},{0.f,0.f,0.f,0.f}};
    #pragma unroll 8
    for (int v = 0; v < 64; v++) {
      float4 w4 = *(const float4*)(w202 + (size_t)(u * 64 + v) * 128 + w0);
      FMA4(a4[0], w4, sL[bA][v]);
      FMA4(a4[1], w4, sL[bB][v]);
    }
    #pragma unroll
    for (int k = 0; k < 5; k++) {
      float fa = dk202[k] * tL[bA][u][k];
      float fb = dk202[k] * tL[bB][u][k];
      #pragma unroll
      for (int wi = 0; wi < 4; wi++) {
        y2acc[k][0][wi] = fmaf(fa, a4[0][wi], y2acc[k][0][wi]);
        y2acc[k][1][wi] = fmaf(fb, a4[1][wi], y2acc[k][1][wi]);
      }
    }
  }
  // tp222
  for (int u = 0; u < 16; u++) {
    for (int idx = tid; idx < 800; idx += 512) {
      int bb = idx / 25, jk = idx - bb * 25;
      float gg = 0.f;
      #pragma unroll
      for (int ii = 0; ii < 5; ii++)
        gg = fmaf(cL222[ii * 25 + jk], tL[bb][u][ii], gg);
      GLb[bb][jk] = gg;
    }
    __syncthreads();
    for (int idx = tid; idx < 2560; idx += 512) {
      int bb = idx / 80, rem = idx - bb * 80;
      int vv = rem / 5, kk = rem - vv * 5;
      float q = 0.f;
      #pragma unroll
      for (int jj = 0; jj < 5; jj++)
        q = fmaf(GLb[bb][jj * 5 + kk], tL[bb][vv][jj], q);
      QLb[bb][vv][kk] = q;
    }
    __syncthreads();
    #pragma unroll 4
    for (int v = 0; v < 16; v++) {
      float4 w4 = *(const float4*)(w222 + (size_t)(u * 16 + v) * 128 + w0);
      #pragma unroll
      for (int k = 0; k < 5; k++) {
        FMA4(y2acc[k][0], w4, QLb[bA][v][k]);
        FMA4(y2acc[k][1], w4, QLb[bB][v][k]);
      }
    }
    __syncthreads();   // QLb reads done
  }
  // scale y2 in registers
  #pragma unroll
  for (int k = 0; k < 5; k++)
    #pragma unroll
    for (int r = 0; r < 2; r++)
      #pragma unroll
      for (int wi = 0; wi < 4; wi++) y2acc[k][r][wi] *= cf.a2;

  // ================= phase 5: tp2, register y2, 2-batch reuse =================
  // 022 path
  {
    float gvr[2][4] = {{0.f,0.f,0.f,0.f},{0.f,0.f,0.f,0.f}};
    #pragma unroll 8
    for (int u = 0; u < 128; u++) {
      float4 w4 = *(const float4*)(w2022 + (size_t)u * 128 + w0);
      FMA4(gvr[0], w4, y0L[bA][u]);
      FMA4(gvr[1], w4, y0L[bB][u]);
    }
    #pragma unroll
    for (int k = 0; k < 5; k++) {
      float pA = gvr[0][0]*y2acc[k][0][0] + gvr[0][1]*y2acc[k][0][1]
               + gvr[0][2]*y2acc[k][0][2] + gvr[0][3]*y2acc[k][0][3];
      float pB = gvr[1][0]*y2acc[k][1][0] + gvr[1][1]*y2acc[k][1][1]
               + gvr[1][2]*y2acc[k][1][2] + gvr[1][3]*y2acc[k][1][3];
      pA += __shfl_xor(pA, 16); pA += __shfl_xor(pA, 8); pA += __shfl_xor(pA, 4);
      pA += __shfl_xor(pA, 2);  pA += __shfl_xor(pA, 1);
      pB += __shfl_xor(pB, 16); pB += __shfl_xor(pB, 8); pB += __shfl_xor(pB, 4);
      pB += __shfl_xor(pB, 2);  pB += __shfl_xor(pB, 1);
      if (xw == 0) {
        corrAcc[bA][k] = dk022[k] * pA;
        corrAcc[bB][k] = dk022[k] * pB;
      }
    }
  }
  // 202 path
  {
    float hvr[2][4] = {{0.f,0.f,0.f,0.f},{0.f,0.f,0.f,0.f}};
    #pragma unroll 8
    for (int v = 0; v < 128; v++) {
      float4 w4 = *(const float4*)(w202T + (size_t)v * 128 + w0);
      FMA4(hvr[0], w4, y0L[bA][v]);
      FMA4(hvr[1], w4, y0L[bB][v]);
    }
    #pragma unroll
    for (int k = 0; k < 5; k++) {
      float pA = hvr[0][0]*y2acc[k][0][0] + hvr[0][1]*y2acc[k][0][1]
               + hvr[0][2]*y2acc[k][0][2] + hvr[0][3]*y2acc[k][0][3];
      float pB = hvr[1][0]*y2acc[k][1][0] + hvr[1][1]*y2acc[k][1][1]
               + hvr[1][2]*y2acc[k][1][2] + hvr[1][3]*y2acc[k][1][3];
      pA += __shfl_xor(pA, 16); pA += __shfl_xor(pA, 8); pA += __shfl_xor(pA, 4);
      pA += __shfl_xor(pA, 2);  pA += __shfl_xor(pA, 1);
      pB += __shfl_xor(pB, 16); pB += __shfl_xor(pB, 8); pB += __shfl_xor(pB, 4);
      pB += __shfl_xor(pB, 2);  pB += __shfl_xor(pB, 1);
      if (xw == 0) {
        corrAcc[bA][k] += dk202[k] * pA;
        corrAcc[bB][k] += dk202[k] * pB;
      }
    }
  }
  // 222 path
  for (int i = 0; i < 5; i++) {
    {
      float4 oa, ob;
      oa.x = y2acc[i][0][0]; oa.y = y2acc[i][0][1];
      oa.z = y2acc[i][0][2]; oa.w = y2acc[i][0][3];
      ob.x = y2acc[i][1][0]; ob.y = y2acc[i][1][1];
      ob.z = y2acc[i][1][2]; ob.w = y2acc[i][1][3];
      *(float4*)(&y2iL[bA][w0]) = oa;
      *(float4*)(&y2iL[bB][w0]) = ob;
    }
    __syncthreads();
    float zr[2][4] = {{0.f,0.f,0.f,0.f},{0.f,0.f,0.f,0.f}};
    #pragma unroll 8
    for (int u = 0; u < 128; u++) {
      float4 w4 = *(const float4*)(w2222 + (size_t)u * 128 + w0);
      FMA4(zr[0], w4, y2iL[bA][u]);
      FMA4(zr[1], w4, y2iL[bB][u]);
    }
    #pragma unroll
    for (int j = 0; j < 5; j++) {
      float pA = zr[0][0]*y2acc[j][0][0] + zr[0][1]*y2acc[j][0][1]
               + zr[0][2]*y2acc[j][0][2] + zr[0][3]*y2acc[j][0][3];
      float pB = zr[1][0]*y2acc[j][1][0] + zr[1][1]*y2acc[j][1][1]
               + zr[1][2]*y2acc[j][1][2] + zr[1][3]*y2acc[j][1][3];
      pA += __shfl_xor(pA, 16); pA += __shfl_xor(pA, 8); pA += __shfl_xor(pA, 4);
      pA += __shfl_xor(pA, 2);  pA += __shfl_xor(pA, 1);
      pB += __shfl_xor(pB, 16); pB += __shfl_xor(pB, 8); pB += __shfl_xor(pB, 4);
      pB += __shfl_xor(pB, 2);  pB += __shfl_xor(pB, 1);
      if (xw == 0) {
        pPL[bA][i * 5 + j] = pA;
        pPL[bB][i * 5 + j] = pB;
      }
    }
    __syncthreads();   // y2iL reads done before next i's overwrite
  }

  // ---- epilogue ----
  if (tid < 160) {
    int bb = tid / 5, k = tid - bb * 5;
    float c2 = 0.f;
    #pragma unroll
    for (int ii = 0; ii < 5; ii++)
      #pragma unroll
      for (int jj = 0; jj < 5; jj++)
        c2 = fmaf(cL222[ii * 25 + jj * 5 + k], pPL[bb][ii * 5 + jj], c2);
    float tot = corrAcc[bb][k] + c2;
    int b = b0 + bb;
    out[(size_t)b * 5 + k] = mixed_ws[(size_t)b * 5 + k] + csc[0] * cf.b2 * tot;
  }
}

// ---------------------------------------------------------------------------
// Host: replicate reference's wigner-3j computation (RREF null space).
// ---------------------------------------------------------------------------
namespace {

using cplx = std::complex<double>;

static void su2_gen(int l, std::vector<cplx>& Jx, std::vector<cplx>& Jy,
                    std::vector<cplx>& Jz) {
  int d = 2 * l + 1;
  Jx.assign((size_t)d * d, cplx(0, 0));
  Jy.assign((size_t)d * d, cplx(0, 0));
  Jz.assign((size_t)d * d, cplx(0, 0));
  for (int a = 0; a < d; a++) Jz[(size_t)a * d + a] = cplx(a - l, 0);
  for (int r = 1; r < d; r++) {
    double m = (r - 1) - l;
    double v = std::sqrt(l * (l + 1.0) - m * (m + 1.0));
    Jx[(size_t)r * d + (r - 1)] += cplx(v / 2, 0);
    Jx[(size_t)(r - 1) * d + r] += cplx(v / 2, 0);
    Jy[(size_t)r * d + (r - 1)] += cplx(0, -v / 2);
    Jy[(size_t)(r - 1) * d + r] += cplx(0, v / 2);
  }
}

static void real_basis(int l, std::vector<cplx>& U) {
  int d = 2 * l + 1;
  U.assign((size_t)d * d, cplx(0, 0));
  U[(size_t)l * d + l] = cplx(1, 0);
  double is2 = 1.0 / std::sqrt(2.0);
  for (int m = 1; m <= l; m++) {
    double sgn = (m % 2 == 0) ? 1.0 : -1.0;
    U[(size_t)(l + m) * d + (l + m)] = cplx(sgn * is2, 0);
    U[(size_t)(l + m) * d + (l - m)] = cplx(is2, 0);
    U[(size_t)(l - m) * d + (l - m)] = cplx(0, is2);
    U[(size_t)(l - m) * d + (l + m)] = cplx(0, -sgn * is2);
  }
}

static void real_gens(int l, std::vector<double> G[3]) {
  int d = 2 * l + 1;
  if (l == 0) { for (int a = 0; a < 3; a++) G[a].assign(1, 0.0); return; }
  std::vector<cplx> J[3];
  su2_gen(l, J[0], J[1], J[2]);
  std::vector<cplx> U;
  real_basis(l, U);
  for (int a = 0; a < 3; a++) {
    std::vector<cplx> T((size_t)d * d, cplx(0, 0));
    for (int i = 0; i < d; i++)
      for (int k = 0; k < d; k++) {
        cplx s(0, 0);
        for (int j = 0; j < d; j++)
          s += U[(size_t)i * d + j] * (cplx(0, -1) * J[a][(size_t)j * d + k]);
        T[(size_t)i * d + k] = s;
      }
    G[a].assign((size_t)d * d, 0.0);
    for (int i = 0; i < d; i++)
      for (int k = 0; k < d; k++) {
        cplx s(0, 0);
        for (int j = 0; j < d; j++)
          s += T[(size_t)i * d + j] * std::conj(U[(size_t)k * d + j]);
        G[a][(size_t)i * d + k] = s.real();
      }
  }
}

static void w3j_host(int l1, int l2, int l3, float* out) {
  int d1 = 2 * l1 + 1, d2 = 2 * l2 + 1, d3 = 2 * l3 + 1;
  int D = d1 * d2 * d3;
  std::vector<double> G1[3], G2[3], G3[3];
  real_gens(l1, G1); real_gens(l2, G2); real_gens(l3, G3);
  int R = 3 * D;
  std::vector<double> M((size_t)R * D, 0.0);
  for (int a = 0; a < 3; a++) {
    double* Ma = &M[(size_t)a * D * D];
    for (int i1 = 0; i1 < d1; i1++)
      for (int j1 = 0; j1 < d1; j1++) {
        double g = G1[a][(size_t)i1 * d1 + j1];
        if (g == 0.0) continue;
        for (int i2 = 0; i2 < d2; i2++)
          for (int i3 = 0; i3 < d3; i3++)
            Ma[(size_t)((i1 * d2 + i2) * d3 + i3) * D + ((j1 * d2 + i2) * d3 + i3)] += g;
      }
    for (int i2 = 0; i2 < d2; i2++)
      for (int j2 = 0; j2 < d2; j2++) {
        double g = G2[a][(size_t)i2 * d2 + j2];
        if (g == 0.0) continue;
        for (int i1 = 0; i1 < d1; i1++)
          for (int i3 = 0; i3 < d3; i3++)
            Ma[(size_t)((i1 * d2 + i2) * d3 + i3) * D + ((i1 * d2 + j2) * d3 + i3)] += g;
      }
    for (int i3 = 0; i3 < d3; i3++)
      for (int j3 = 0; j3 < d3; j3++) {
        double g = G3[a][(size_t)i3 * d3 + j3];
        if (g == 0.0) continue;
        for (int i1 = 0; i1 < d1; i1++)
          for (int i2 = 0; i2 < d2; i2++)
            Ma[(size_t)((i1 * d2 + i2) * d3 + i3) * D + ((i1 * d2 + i2) * d3 + j3)] += g;
      }
  }
  std::vector<int> pivcol;
  int rank = 0;
  for (int col = 0; col < D && rank < R; col++) {
    int pr = -1; double pv = 1e-9;
    for (int r = rank; r < R; r++) {
      double av = std::fabs(M[(size_t)r * D + col]);
      if (av > pv) { pv = av; pr = r; }
    }
    if (pr < 0) continue;
    if (pr != rank)
      for (int c = 0; c < D; c++) std::swap(M[(size_t)pr * D + c], M[(size_t)rank * D + c]);
    double inv = 1.0 / M[(size_t)rank * D + col];
    for (int c = 0; c < D; c++) M[(size_t)rank * D + c] *= inv;
    for (int r = 0; r < R; r++) {
      if (r == rank) continue;
      double f = M[(size_t)r * D + col];
      if (f != 0.0)
        for (int c = 0; c < D; c++) M[(size_t)r * D + c] -= f * M[(size_t)rank * D + c];
    }
    pivcol.push_back(col);
    rank++;
  }
  std::vector<char> isp(D, 0);
  for (int c : pivcol) isp[c] = 1;
  int fc = 0;
  for (int c = 0; c < D; c++) if (!isp[c]) { fc = c; break; }
  std::vector<double> x(D, 0.0);
  x[fc] = 1.0;
  for (int r = 0; r < rank; r++) x[pivcol[r]] = -M[(size_t)r * D + fc];
  double n = 0;
  for (double v : x) n += v * v;
  n = std::sqrt(n);
  for (int c = 0; c < D; c++) x[c] /= n;
  double best = 0;
  for (int c = 0; c < D; c++) { double av = std::fabs(x[c]); if (av > best) best = av; }
  double ssum = 0;
  for (int c = 0; c < D; c++) {
    double av = std::fabs(x[c]);
    if (av >= best * 0.999) ssum += (x[c] >= 0 ? 1.0 : -1.0);
  }
  double sgn = (ssum >= 0) ? 1.0 : -1.0;
  for (int c = 0; c < D; c++) out[c] = (float)(x[c] * sgn);
}

}  // namespace

// ---------------------------------------------------------------------------
extern "C" void kernel_launch(void* const* d_in, const int* in_sizes, int n_in,
                              void* d_out, int out_size, void* d_ws, size_t ws_size,
                              hipStream_t stream)
{
  (void)in_sizes; (void)n_in; (void)out_size; (void)ws_size;

  const float* s     = (const float*)d_in[0];
  const float* t2s   = (const float*)d_in[1];
  const float* w1    = (const float*)d_in[2];
  const float* w2    = (const float*)d_in[3];
  const float* w3    = (const float*)d_in[4];
  const float* gthr  = (const float*)d_in[5];
  const float* w000  = (const float*)d_in[6];
  const float* w220  = (const float*)d_in[7];
  const float* w022  = (const float*)d_in[8];
  const float* w202  = (const float*)d_in[9];
  const float* w222  = (const float*)d_in[10];
  const float* w2022 = (const float*)d_in[11];
  const float* w2202 = (const float*)d_in[12];
  const float* w2222 = (const float*)d_in[13];
  const float* csc   = (const float*)d_in[14];
  float* out = (float*)d_out;

  char* ws = (char*)d_ws;
  float* mixed_ws = (float*)(ws + MIX_WS_OFF);
  float* w202T    = (float*)(ws + W202T_OFF);
  float* wsym     = (float*)(ws + WSYM_OFF);
  float* w022T    = (float*)(ws + W022T_OFF);

  Coefs cf;
  {
    float c000v[1], c022v[25], c202v[25], c220v[25];
    w3j_host(0, 0, 0, c000v);
    w3j_host(0, 2, 2, c022v);
    w3j_host(2, 0, 2, c202v);
    w3j_host(2, 2, 0, c220v);
    w3j_host(2, 2, 2, cf.c222);
    for (int i = 0; i < 125; i++) cf.c222[i] *= C222_FLIP;
    for (int k = 0; k < 5; k++) {
      cf.d022[k] = c022v[k * 5 + k];
      cf.d202[k] = c202v[k * 5 + k];
      cf.d220[k] = c220v[k * 5 + k];
    }
    (void)c000v;
    cf.a0 = (float)std::sqrt(1.0 / (64.0 * 64.0 + 16.0 * 16.0));
    cf.a2 = (float)std::sqrt(5.0 / (2.0 * 64.0 * 16.0 + 16.0 * 16.0));
    cf.b2 = (float)std::sqrt(5.0 / (3.0 * 128.0 * 128.0));
  }

  hipLaunchKernelGGL(k_prep, dim3(512), dim3(256), 0, stream,
                     s, t2s, w1, w2, w3, gthr, mixed_ws);
  hipLaunchKernelGGL(k_wprep, dim3(256), dim3(256), 0, stream,
                     w000, wsym, w2202, w202T, w022, w022T);
  hipLaunchKernelGGL(k_fused, dim3(512), dim3(512), 0, stream,
                     s, t2s, mixed_ws, wsym, w220, w022T, w202, w222,
                     w2022, w202T, w2222, csc, out, cf);
}

// Round 9
// 831.641 us; speedup vs baseline: 2.1969x; 1.0211x over previous
//
#include <hip/hip_runtime.h>
#include <hip/hip_bf16.h>
#include <cmath>
#include <complex>
#include <vector>
#include <cstring>
#include <cstdint>

// ---------------------------------------------------------------------------
// ShieldingT2Model: f32, round 9 — r8 with the GI staging bounds bug fixed.
// B=16384, NS=64, NK=32, NL=16, HM=256, HC=128, out = (B,5) f32.
//
// r7 2-batch weight reuse     :  849 us, VALU 45% (LDS pipe co-limiter)
// r8 interleaved-pair LDS     :  FAILED — G-staging loop iterated 1600 (not
//    800), jk ran 0..49: OOB read of cL222 + OOB write of GI => tp222 garbage.
// r9: fix = idx<800, g_=idx/50, jk=(idx%50)>>1, h=idx&1. Nothing else changed.
//
// ws (~2 MB): mixed @0 | w202T @327680 | wsym @393216 | w022T @1458176
// C222 sign: majority-positive canonicalization, then flipped (r2/r3 A/B).
// ---------------------------------------------------------------------------

#define C222_FLIP -1.0f

#define MIX_WS_OFF   0
#define W202T_OFF    327680
#define WSYM_OFF     393216
#define W022T_OFF    1458176

struct Coefs {
  float c222[125];   // full (2,2,2) real wigner-3j, [i][j][k]
  float d022[5];     // diag of C022[0,:,:]
  float d202[5];     // diag of C202[:,0,:]
  float d220[5];     // diag of C220[:,:,0]
  float a0, a2, b2;
};

#define FMA8(acc, wa, wb, sv) do { \
  acc[0] = fmaf((wa).x, (sv), acc[0]); \
  acc[1] = fmaf((wa).y, (sv), acc[1]); \
  acc[2] = fmaf((wa).z, (sv), acc[2]); \
  acc[3] = fmaf((wa).w, (sv), acc[3]); \
  acc[4] = fmaf((wb).x, (sv), acc[4]); \
  acc[5] = fmaf((wb).y, (sv), acc[5]); \
  acc[6] = fmaf((wb).z, (sv), acc[6]); \
  acc[7] = fmaf((wb).w, (sv), acc[7]); \
} while (0)

#define FMA4(acc, wa, sv) do { \
  acc[0] = fmaf((wa).x, (sv), acc[0]); \
  acc[1] = fmaf((wa).y, (sv), acc[1]); \
  acc[2] = fmaf((wa).z, (sv), acc[2]); \
  acc[3] = fmaf((wa).w, (sv), acc[3]); \
} while (0)

__device__ __forceinline__ float act_silu(float x) {
  return 1.679f * x / (1.0f + expf(-x));   // SILU_NORM * silu(x)
}

// ---------------------------------------------------------------------------
// K1: MLP -> weights -> mixed.  32 b per wg, 256 threads. (proven)
// ---------------------------------------------------------------------------
__global__ __launch_bounds__(256) void k_prep(
    const float* __restrict__ s, const float* __restrict__ t2s,
    const float* __restrict__ w1, const float* __restrict__ w2,
    const float* __restrict__ w3, const float* __restrict__ gthr,
    float* __restrict__ mixed_ws)
{
  __shared__ float sT[64][36];    // [k][b], padded
  __shared__ float hT[256][36];   // [c][b], holds h1 then h2

  const int tid = threadIdx.x;
  const int b0  = blockIdx.x * 32;

  #pragma unroll
  for (int i = 0; i < 8; i++) {
    int flat = tid + i * 256;
    int bl = flat >> 6, k = flat & 63;
    sT[k][bl] = s[(size_t)(b0 + bl) * 64 + k];
  }
  __syncthreads();

  const int cg = tid & 31, bg = tid >> 5;
  const int c0 = cg * 8, bb0 = bg * 4;

  float acc[4][8];
  #pragma unroll
  for (int j = 0; j < 4; j++)
    #pragma unroll
    for (int i = 0; i < 8; i++) acc[j][i] = 0.f;

  for (int k = 0; k < 64; k++) {
    float4 bv = *(const float4*)&sT[k][bb0];
    float4 wa = *(const float4*)&w1[k * 256 + c0];
    float4 wb = *(const float4*)&w1[k * 256 + c0 + 4];
    const float bvv[4] = {bv.x, bv.y, bv.z, bv.w};
    #pragma unroll
    for (int j = 0; j < 4; j++) { FMA8(acc[j], wa, wb, bvv[j]); }
  }
  #pragma unroll
  for (int j = 0; j < 4; j++)
    #pragma unroll
    for (int i = 0; i < 8; i++)
      hT[c0 + i][bb0 + j] = act_silu(acc[j][i] * 0.125f);
  __syncthreads();

  float acc2[4][8];
  #pragma unroll
  for (int j = 0; j < 4; j++)
    #pragma unroll
    for (int i = 0; i < 8; i++) acc2[j][i] = 0.f;

  for (int k = 0; k < 256; k++) {
    float4 bv = *(const float4*)&hT[k][bb0];
    float4 wa = *(const float4*)&w2[k * 256 + c0];
    float4 wb = *(const float4*)&w2[k * 256 + c0 + 4];
    const float bvv[4] = {bv.x, bv.y, bv.z, bv.w};
    #pragma unroll
    for (int j = 0; j < 4; j++) { FMA8(acc2[j], wa, wb, bvv[j]); }
  }
  __syncthreads();
  #pragma unroll
  for (int j = 0; j < 4; j++)
    #pragma unroll
    for (int i = 0; i < 8; i++)
      hT[c0 + i][bb0 + j] = act_silu(acc2[j][i] * 0.0625f);
  __syncthreads();

  const int jj  = tid & 31;
  const int blg = tid >> 5;
  float acc3[4] = {0.f, 0.f, 0.f, 0.f};
  for (int k = 0; k < 256; k++) {
    float wv  = w3[k * 32 + jj];
    float4 hv = *(const float4*)&hT[k][blg * 4];
    acc3[0] = fmaf(hv.x, wv, acc3[0]);
    acc3[1] = fmaf(hv.y, wv, acc3[1]);
    acc3[2] = fmaf(hv.z, wv, acc3[2]);
    acc3[3] = fmaf(hv.w, wv, acc3[3]);
  }
  const float thrv = gthr[jj];
  #pragma unroll
  for (int r = 0; r < 4; r++) {
    int bl = blg * 4 + r;
    int b  = b0 + bl;
    float rel = acc3[r] * 0.0625f;
    const float* tp = t2s + (size_t)(b * 32 + jj) * 5;
    float tv0 = tp[0], tv1 = tp[1], tv2 = tp[2], tv3 = tp[3], tv4 = tp[4];
    float mag  = sqrtf(tv0*tv0 + tv1*tv1 + tv2*tv2 + tv3*tv3 + tv4*tv4);
    float gate = mag / (mag + thrv);
    float w = rel * gate * 0.17677669529663687f;  // 1/sqrt(32)
    float pm0 = w*tv0, pm1 = w*tv1, pm2 = w*tv2, pm3 = w*tv3, pm4 = w*tv4;
    #pragma unroll
    for (int off = 16; off >= 1; off >>= 1) {
      pm0 += __shfl_xor(pm0, off);
      pm1 += __shfl_xor(pm1, off);
      pm2 += __shfl_xor(pm2, off);
      pm3 += __shfl_xor(pm3, off);
      pm4 += __shfl_xor(pm4, off);
    }
    if (jj == 0) {
      float* mp = mixed_ws + (size_t)b * 5;
      mp[0] = pm0; mp[1] = pm1; mp[2] = pm2; mp[3] = pm3; mp[4] = pm4;
    }
  }
}

// ---------------------------------------------------------------------------
// K2: merged weight prep (unchanged).
// ---------------------------------------------------------------------------
__global__ __launch_bounds__(256) void k_wprep(
    const float* __restrict__ w000, float* __restrict__ wsym,
    const float* __restrict__ w2202, float* __restrict__ w202T,
    const float* __restrict__ w022, float* __restrict__ w022T)
{
  const int tid = threadIdx.x;
  const int blk = blockIdx.x;
  if (blk < 64) {
    int u = blk;
    int base = u * 64 - (u * (u - 1)) / 2;
    int n = (64 - u) * 128;
    for (int idx = tid; idx < n; idx += 256) {
      int t = idx >> 7, wc = idx & 127;
      int v = u + t;
      float val = w000[(size_t)(u * 64 + v) * 128 + wc];
      if (v > u) val += w000[(size_t)(v * 64 + u) * 128 + wc];
      wsym[(size_t)(base + t) * 128 + wc] = val;
    }
  } else if (blk < 128) {
    int idx = (blk - 64) * 256 + tid;  // 16384
    int u = idx >> 7, v = idx & 127;
    w202T[v * 128 + u] = w2202[u * 128 + v];
  } else {
    int e0 = (blk - 128) * 1024;       // 128 blocks x 1024 = 131072
    #pragma unroll
    for (int i = 0; i < 4; i++) {
      int e = e0 + i * 256 + tid;
      int w = e & 127, r = e >> 7;     // r = u*16+v
      int u = r >> 4, v = r & 15;
      w022T[(size_t)(v * 64 + u) * 128 + w] = w022[e];
    }
  }
}

// ---------------------------------------------------------------------------
// K3: fused heavy kernel. 32 b per block, 512 blocks, 512 threads, ~72KB LDS.
// thread map: xw = tid&31 (channel quad w0=xw*4), g = tid>>5 (0..15),
// batches bA=2g, bB=2g+1 interleaved in LDS as [..][2] -> ds_read_b64.
// ---------------------------------------------------------------------------
__global__ __launch_bounds__(512, 4) void k_fused(
    const float* __restrict__ s, const float* __restrict__ t2s,
    const float* __restrict__ mixed_ws,
    const float* __restrict__ wsym,  const float* __restrict__ w220,
    const float* __restrict__ w022T, const float* __restrict__ w202,
    const float* __restrict__ w222,
    const float* __restrict__ w2022, const float* __restrict__ w202T,
    const float* __restrict__ w2222,
    const float* __restrict__ csc, float* __restrict__ out, Coefs cf)
{
  __shared__ __align__(16) float sI[16][64][2];    //  8192 B
  __shared__ __align__(16) float tI[16][16][5][2]; // 10240 B
  __shared__ __align__(16) float y0I[16][128][2];  // 16384 B
  __shared__ float cL222[125];                     //   500 B
  __shared__ float corrAcc[32][5];                 //   640 B
  __shared__ float pPL[32][25];                    //  3200 B
  __shared__ __align__(16) char uni[32768];        // union (time-disjoint):
  //   y220 : grI  = float[16][256][2]  (32768 B) @ uni
  //   tp222: GI = float[16][25][2] (3200) @ uni ; QI = float[16][16][5][2] @+3200
  //   ph5  : y2iI = float[16][128][2] (16384 B) @ uni
  float (*grI)[256][2]   = (float(*)[256][2])uni;
  float (*GI)[25][2]     = (float(*)[25][2])uni;
  float (*QI)[16][5][2]  = (float(*)[16][5][2])(uni + 3200);
  float (*y2iI)[128][2]  = (float(*)[128][2])uni;
  // total ~71.9 KB -> 2 blocks/CU

  const int tid = threadIdx.x;
  const int b0  = blockIdx.x * 32;

  float dk022[5], dk202[5], dk220[5];
  #pragma unroll
  for (int k = 0; k < 5; k++) {
    dk022[k] = cf.d022[k]; dk202[k] = cf.d202[k]; dk220[k] = cf.d220[k];
  }

  // ---- stage (interleaved pair layouts) ----
  if (tid == 0) {
    #pragma unroll
    for (int i = 0; i < 125; i++) cL222[i] = cf.c222[i];
  }
  for (int idx = tid; idx < 32 * 64; idx += 512) {
    int bl = idx >> 6, k = idx & 63;
    sI[bl >> 1][k][bl & 1] = s[(size_t)(b0 + bl) * 64 + k];
  }
  for (int idx = tid; idx < 32 * 80; idx += 512) {
    int bl = idx / 80, rem = idx - bl * 80;
    int u = rem / 5, m = rem - u * 5;
    int b = b0 + bl;
    float v;
    if (u < 15) v = t2s[(size_t)(b * 32 + u) * 5 + m];
    else {
      v = 0.f;
      for (int kk = 0; kk < 32; kk++) v += t2s[(size_t)(b * 32 + kk) * 5 + m];
    }
    tI[bl >> 1][u][m][bl & 1] = v;
  }
  __syncthreads();

  // gram for all (g,u,v,h) -> grI
  for (int idx = tid; idx < 8192; idx += 512) {
    int g_ = idx >> 9, r = (idx >> 1) & 255, h = idx & 1;
    int u = r >> 4, v = r & 15;
    float gg = 0.f;
    #pragma unroll
    for (int m = 0; m < 5; m++)
      gg = fmaf(dk220[m] * tI[g_][u][m][h], tI[g_][v][m][h], gg);
    grI[g_][r][h] = gg;
  }
  __syncthreads();

  const int xw = tid & 31;
  const int g  = tid >> 5;
  const int w0 = xw * 4;

  // ---- y000: two-level, su in regs, z-accumulate. 1 ds_read_b64/iter ----
  float y0a[2][4] = {{0.f,0.f,0.f,0.f},{0.f,0.f,0.f,0.f}};
  {
    const float* wp = wsym + w0;
    for (int u = 0; u < 64; u++) {
      float2 su = *(const float2*)&sI[g][u][0];
      float zA[4] = {0.f,0.f,0.f,0.f}, zB[4] = {0.f,0.f,0.f,0.f};
      const int len = 64 - u;
      #pragma unroll 8
      for (int t = 0; t < len; t++) {
        float2 sv = *(const float2*)&sI[g][u + t][0];
        float4 w4 = *(const float4*)wp;
        FMA4(zA, w4, sv.x);
        FMA4(zB, w4, sv.y);
        wp += 128;
      }
      #pragma unroll
      for (int wi = 0; wi < 4; wi++) {
        y0a[0][wi] = fmaf(su.x, zA[wi], y0a[0][wi]);
        y0a[1][wi] = fmaf(su.y, zB[wi], y0a[1][wi]);
      }
    }
  }
  // ---- y220: flat 256 loop, 1 ds_read_b64/iter ----
  #pragma unroll 8
  for (int q = 0; q < 256; q++) {
    float2 gr = *(const float2*)&grI[g][q][0];
    float4 w4 = *(const float4*)(w220 + (size_t)q * 128 + w0);
    FMA4(y0a[0], w4, gr.x);
    FMA4(y0a[1], w4, gr.y);
  }
  #pragma unroll
  for (int wi = 0; wi < 4; wi++) {
    float2 o; o.x = cf.a0 * y0a[0][wi]; o.y = cf.a0 * y0a[1][wi];
    *(float2*)&y0I[g][w0 + wi][0] = o;
  }
  __syncthreads();  // grI dead; y0I published

  // ---- y2 (registers, both batches) ----
  float y2acc[5][2][4];
  #pragma unroll
  for (int k = 0; k < 5; k++)
    #pragma unroll
    for (int r = 0; r < 2; r++)
      #pragma unroll
      for (int wi = 0; wi < 4; wi++) y2acc[k][r][wi] = 0.f;

  // tp022 (w022T: [v][u][w] contiguous; 1 ds_read_b64/iter)
  for (int v = 0; v < 16; v++) {
    float a4[2][4] = {{0.f,0.f,0.f,0.f},{0.f,0.f,0.f,0.f}};
    #pragma unroll 8
    for (int u = 0; u < 64; u++) {
      float2 su = *(const float2*)&sI[g][u][0];
      float4 w4 = *(const float4*)(w022T + (size_t)(v * 64 + u) * 128 + w0);
      FMA4(a4[0], w4, su.x);
      FMA4(a4[1], w4, su.y);
    }
    #pragma unroll
    for (int k = 0; k < 5; k++) {
      float2 tv = *(const float2*)&tI[g][v][k][0];
      float fa = dk022[k] * tv.x;
      float fb = dk022[k] * tv.y;
      #pragma unroll
      for (int wi = 0; wi < 4; wi++) {
        y2acc[k][0][wi] = fmaf(fa, a4[0][wi], y2acc[k][0][wi]);
        y2acc[k][1][wi] = fmaf(fb, a4[1][wi], y2acc[k][1][wi]);
      }
    }
  }
  // tp202 (original w202 [u][v][w], contiguous in v)
  for (int u = 0; u < 16; u++) {
    float a4[2][4] = {{0.f,0.f,0.f,0.f},{0.f,0.f,0.f,0.f}};
    #pragma unroll 8
    for (int v = 0; v < 64; v++) {
      float2 sv = *(const float2*)&sI[g][v][0];
      float4 w4 = *(const float4*)(w202 + (size_t)(u * 64 + v) * 128 + w0);
      FMA4(a4[0], w4, sv.x);
      FMA4(a4[1], w4, sv.y);
    }
    #pragma unroll
    for (int k = 0; k < 5; k++) {
      float2 tu = *(const float2*)&tI[g][u][k][0];
      float fa = dk202[k] * tu.x;
      float fb = dk202[k] * tu.y;
      #pragma unroll
      for (int wi = 0; wi < 4; wi++) {
        y2acc[k][0][wi] = fmaf(fa, a4[0][wi], y2acc[k][0][wi]);
        y2acc[k][1][wi] = fmaf(fb, a4[1][wi], y2acc[k][1][wi]);
      }
    }
  }
  // tp222
  for (int u = 0; u < 16; u++) {
    // G staging: 16 g x 25 jk x 2 h = 800 elements  (r8 bug was idx<1600/jk..49)
    for (int idx = tid; idx < 800; idx += 512) {
      int g_ = idx / 50, rem = idx - g_ * 50;
      int jk = rem >> 1, h = rem & 1;
      float gg = 0.f;
      #pragma unroll
      for (int ii = 0; ii < 5; ii++)
        gg = fmaf(cL222[ii * 25 + jk], tI[g_][u][ii][h], gg);
      GI[g_][jk][h] = gg;
    }
    __syncthreads();
    for (int idx = tid; idx < 2560; idx += 512) {
      int g_ = idx / 160, rem = idx - g_ * 160;
      int vv = rem / 10, r2 = rem - vv * 10;
      int kk = r2 >> 1, h = r2 & 1;
      float q = 0.f;
      #pragma unroll
      for (int jj = 0; jj < 5; jj++)
        q = fmaf(GI[g_][jj * 5 + kk][h], tI[g_][vv][jj][h], q);
      QI[g_][vv][kk][h] = q;
    }
    __syncthreads();
    #pragma unroll 4
    for (int v = 0; v < 16; v++) {
      float4 w4 = *(const float4*)(w222 + (size_t)(u * 16 + v) * 128 + w0);
      #pragma unroll
      for (int k = 0; k < 5; k++) {
        float2 q2 = *(const float2*)&QI[g][v][k][0];
        FMA4(y2acc[k][0], w4, q2.x);
        FMA4(y2acc[k][1], w4, q2.y);
      }
    }
    __syncthreads();   // QI reads done
  }
  // scale y2 in registers
  #pragma unroll
  for (int k = 0; k < 5; k++)
    #pragma unroll
    for (int r = 0; r < 2; r++)
      #pragma unroll
      for (int wi = 0; wi < 4; wi++) y2acc[k][r][wi] *= cf.a2;

  // ================= phase 5: tp2, register y2, paired LDS =================
  const int bA = 2 * g, bB = 2 * g + 1;
  // 022 path
  {
    float gvr[2][4] = {{0.f,0.f,0.f,0.f},{0.f,0.f,0.f,0.f}};
    #pragma unroll 8
    for (int u = 0; u < 128; u++) {
      float2 y0p = *(const float2*)&y0I[g][u][0];
      float4 w4 = *(const float4*)(w2022 + (size_t)u * 128 + w0);
      FMA4(gvr[0], w4, y0p.x);
      FMA4(gvr[1], w4, y0p.y);
    }
    #pragma unroll
    for (int k = 0; k < 5; k++) {
      float pA = gvr[0][0]*y2acc[k][0][0] + gvr[0][1]*y2acc[k][0][1]
               + gvr[0][2]*y2acc[k][0][2] + gvr[0][3]*y2acc[k][0][3];
      float pB = gvr[1][0]*y2acc[k][1][0] + gvr[1][1]*y2acc[k][1][1]
               + gvr[1][2]*y2acc[k][1][2] + gvr[1][3]*y2acc[k][1][3];
      pA += __shfl_xor(pA, 16); pA += __shfl_xor(pA, 8); pA += __shfl_xor(pA, 4);
      pA += __shfl_xor(pA, 2);  pA += __shfl_xor(pA, 1);
      pB += __shfl_xor(pB, 16); pB += __shfl_xor(pB, 8); pB += __shfl_xor(pB, 4);
      pB += __shfl_xor(pB, 2);  pB += __shfl_xor(pB, 1);
      if (xw == 0) {
        corrAcc[bA][k] = dk022[k] * pA;
        corrAcc[bB][k] = dk022[k] * pB;
      }
    }
  }
  // 202 path
  {
    float hvr[2][4] = {{0.f,0.f,0.f,0.f},{0.f,0.f,0.f,0.f}};
    #pragma unroll 8
    for (int v = 0; v < 128; v++) {
      float2 y0p = *(const float2*)&y0I[g][v][0];
      float4 w4 = *(const float4*)(w202T + (size_t)v * 128 + w0);
      FMA4(hvr[0], w4, y0p.x);
      FMA4(hvr[1], w4, y0p.y);
    }
    #pragma unroll
    for (int k = 0; k < 5; k++) {
      float pA = hvr[0][0]*y2acc[k][0][0] + hvr[0][1]*y2acc[k][0][1]
               + hvr[0][2]*y2acc[k][0][2] + hvr[0][3]*y2acc[k][0][3];
      float pB = hvr[1][0]*y2acc[k][1][0] + hvr[1][1]*y2acc[k][1][1]
               + hvr[1][2]*y2acc[k][1][2] + hvr[1][3]*y2acc[k][1][3];
      pA += __shfl_xor(pA, 16); pA += __shfl_xor(pA, 8); pA += __shfl_xor(pA, 4);
      pA += __shfl_xor(pA, 2);  pA += __shfl_xor(pA, 1);
      pB += __shfl_xor(pB, 16); pB += __shfl_xor(pB, 8); pB += __shfl_xor(pB, 4);
      pB += __shfl_xor(pB, 2);  pB += __shfl_xor(pB, 1);
      if (xw == 0) {
        corrAcc[bA][k] += dk202[k] * pA;
        corrAcc[bB][k] += dk202[k] * pB;
      }
    }
  }
  // 222 path
  for (int i = 0; i < 5; i++) {
    #pragma unroll
    for (int wi = 0; wi < 4; wi++) {
      float2 o; o.x = y2acc[i][0][wi]; o.y = y2acc[i][1][wi];
      *(float2*)&y2iI[g][w0 + wi][0] = o;
    }
    __syncthreads();
    float zr[2][4] = {{0.f,0.f,0.f,0.f},{0.f,0.f,0.f,0.f}};
    #pragma unroll 8
    for (int u = 0; u < 128; u++) {
      float2 yp = *(const float2*)&y2iI[g][u][0];
      float4 w4 = *(const float4*)(w2222 + (size_t)u * 128 + w0);
      FMA4(zr[0], w4, yp.x);
      FMA4(zr[1], w4, yp.y);
    }
    #pragma unroll
    for (int j = 0; j < 5; j++) {
      float pA = zr[0][0]*y2acc[j][0][0] + zr[0][1]*y2acc[j][0][1]
               + zr[0][2]*y2acc[j][0][2] + zr[0][3]*y2acc[j][0][3];
      float pB = zr[1][0]*y2acc[j][1][0] + zr[1][1]*y2acc[j][1][1]
               + zr[1][2]*y2acc[j][1][2] + zr[1][3]*y2acc[j][1][3];
      pA += __shfl_xor(pA, 16); pA += __shfl_xor(pA, 8); pA += __shfl_xor(pA, 4);
      pA += __shfl_xor(pA, 2);  pA += __shfl_xor(pA, 1);
      pB += __shfl_xor(pB, 16); pB += __shfl_xor(pB, 8); pB += __shfl_xor(pB, 4);
      pB += __shfl_xor(pB, 2);  pB += __shfl_xor(pB, 1);
      if (xw == 0) {
        pPL[bA][i * 5 + j] = pA;
        pPL[bB][i * 5 + j] = pB;
      }
    }
    __syncthreads();   // y2iI reads done before next i's overwrite
  }

  // ---- epilogue ----
  if (tid < 160) {
    int bb = tid / 5, k = tid - bb * 5;
    float c2 = 0.f;
    #pragma unroll
    for (int ii = 0; ii < 5; ii++)
      #pragma unroll
      for (int jj = 0; jj < 5; jj++)
        c2 = fmaf(cL222[ii * 25 + jj * 5 + k], pPL[bb][ii * 5 + jj], c2);
    float tot = corrAcc[bb][k] + c2;
    int b = b0 + bb;
    out[(size_t)b * 5 + k] = mixed_ws[(size_t)b * 5 + k] + csc[0] * cf.b2 * tot;
  }
}

// ---------------------------------------------------------------------------
// Host: replicate reference's wigner-3j computation (RREF null space).
// ---------------------------------------------------------------------------
namespace {

using cplx = std::complex<double>;

static void su2_gen(int l, std::vector<cplx>& Jx, std::vector<cplx>& Jy,
                    std::vector<cplx>& Jz) {
  int d = 2 * l + 1;
  Jx.assign((size_t)d * d, cplx(0, 0));
  Jy.assign((size_t)d * d, cplx(0, 0));
  Jz.assign((size_t)d * d, cplx(0, 0));
  for (int a = 0; a < d; a++) Jz[(size_t)a * d + a] = cplx(a - l, 0);
  for (int r = 1; r < d; r++) {
    double m = (r - 1) - l;
    double v = std::sqrt(l * (l + 1.0) - m * (m + 1.0));
    Jx[(size_t)r * d + (r - 1)] += cplx(v / 2, 0);
    Jx[(size_t)(r - 1) * d + r] += cplx(v / 2, 0);
    Jy[(size_t)r * d + (r - 1)] += cplx(0, -v / 2);
    Jy[(size_t)(r - 1) * d + r] += cplx(0, v / 2);
  }
}

static void real_basis(int l, std::vector<cplx>& U) {
  int d = 2 * l + 1;
  U.assign((size_t)d * d, cplx(0, 0));
  U[(size_t)l * d + l] = cplx(1, 0);
  double is2 = 1.0 / std::sqrt(2.0);
  for (int m = 1; m <= l; m++) {
    double sgn = (m % 2 == 0) ? 1.0 : -1.0;
    U[(size_t)(l + m) * d + (l + m)] = cplx(sgn * is2, 0);
    U[(size_t)(l + m) * d + (l - m)] = cplx(is2, 0);
    U[(size_t)(l - m) * d + (l - m)] = cplx(0, is2);
    U[(size_t)(l - m) * d + (l + m)] = cplx(0, -sgn * is2);
  }
}

static void real_gens(int l, std::vector<double> G[3]) {
  int d = 2 * l + 1;
  if (l == 0) { for (int a = 0; a < 3; a++) G[a].assign(1, 0.0); return; }
  std::vector<cplx> J[3];
  su2_gen(l, J[0], J[1], J[2]);
  std::vector<cplx> U;
  real_basis(l, U);
  for (int a = 0; a < 3; a++) {
    std::vector<cplx> T((size_t)d * d, cplx(0, 0));
    for (int i = 0; i < d; i++)
      for (int k = 0; k < d; k++) {
        cplx s(0, 0);
        for (int j = 0; j < d; j++)
          s += U[(size_t)i * d + j] * (cplx(0, -1) * J[a][(size_t)j * d + k]);
        T[(size_t)i * d + k] = s;
      }
    G[a].assign((size_t)d * d, 0.0);
    for (int i = 0; i < d; i++)
      for (int k = 0; k < d; k++) {
        cplx s(0, 0);
        for (int j = 0; j < d; j++)
          s += T[(size_t)i * d + j] * std::conj(U[(size_t)k * d + j]);
        G[a][(size_t)i * d + k] = s.real();
      }
  }
}

static void w3j_host(int l1, int l2, int l3, float* out) {
  int d1 = 2 * l1 + 1, d2 = 2 * l2 + 1, d3 = 2 * l3 + 1;
  int D = d1 * d2 * d3;
  std::vector<double> G1[3], G2[3], G3[3];
  real_gens(l1, G1); real_gens(l2, G2); real_gens(l3, G3);
  int R = 3 * D;
  std::vector<double> M((size_t)R * D, 0.0);
  for (int a = 0; a < 3; a++) {
    double* Ma = &M[(size_t)a * D * D];
    for (int i1 = 0; i1 < d1; i1++)
      for (int j1 = 0; j1 < d1; j1++) {
        double g = G1[a][(size_t)i1 * d1 + j1];
        if (g == 0.0) continue;
        for (int i2 = 0; i2 < d2; i2++)
          for (int i3 = 0; i3 < d3; i3++)
            Ma[(size_t)((i1 * d2 + i2) * d3 + i3) * D + ((j1 * d2 + i2) * d3 + i3)] += g;
      }
    for (int i2 = 0; i2 < d2; i2++)
      for (int j2 = 0; j2 < d2; j2++) {
        double g = G2[a][(size_t)i2 * d2 + j2];
        if (g == 0.0) continue;
        for (int i1 = 0; i1 < d1; i1++)
          for (int i3 = 0; i3 < d3; i3++)
            Ma[(size_t)((i1 * d2 + i2) * d3 + i3) * D + ((i1 * d2 + j2) * d3 + i3)] += g;
      }
    for (int i3 = 0; i3 < d3; i3++)
      for (int j3 = 0; j3 < d3; j3++) {
        double g = G3[a][(size_t)i3 * d3 + j3];
        if (g == 0.0) continue;
        for (int i1 = 0; i1 < d1; i1++)
          for (int i2 = 0; i2 < d2; i2++)
            Ma[(size_t)((i1 * d2 + i2) * d3 + i3) * D + ((i1 * d2 + i2) * d3 + j3)] += g;
      }
  }
  std::vector<int> pivcol;
  int rank = 0;
  for (int col = 0; col < D && rank < R; col++) {
    int pr = -1; double pv = 1e-9;
    for (int r = rank; r < R; r++) {
      double av = std::fabs(M[(size_t)r * D + col]);
      if (av > pv) { pv = av; pr = r; }
    }
    if (pr < 0) continue;
    if (pr != rank)
      for (int c = 0; c < D; c++) std::swap(M[(size_t)pr * D + c], M[(size_t)rank * D + c]);
    double inv = 1.0 / M[(size_t)rank * D + col];
    for (int c = 0; c < D; c++) M[(size_t)rank * D + c] *= inv;
    for (int r = 0; r < R; r++) {
      if (r == rank) continue;
      double f = M[(size_t)r * D + col];
      if (f != 0.0)
        for (int c = 0; c < D; c++) M[(size_t)r * D + c] -= f * M[(size_t)rank * D + c];
    }
    pivcol.push_back(col);
    rank++;
  }
  std::vector<char> isp(D, 0);
  for (int c : pivcol) isp[c] = 1;
  int fc = 0;
  for (int c = 0; c < D; c++) if (!isp[c]) { fc = c; break; }
  std::vector<double> x(D, 0.0);
  x[fc] = 1.0;
  for (int r = 0; r < rank; r++) x[pivcol[r]] = -M[(size_t)r * D + fc];
  double n = 0;
  for (double v : x) n += v * v;
  n = std::sqrt(n);
  for (int c = 0; c < D; c++) x[c] /= n;
  double best = 0;
  for (int c = 0; c < D; c++) { double av = std::fabs(x[c]); if (av > best) best = av; }
  double ssum = 0;
  for (int c = 0; c < D; c++) {
    double av = std::fabs(x[c]);
    if (av >= best * 0.999) ssum += (x[c] >= 0 ? 1.0 : -1.0);
  }
  double sgn = (ssum >= 0) ? 1.0 : -1.0;
  for (int c = 0; c < D; c++) out[c] = (float)(x[c] * sgn);
}

}  // namespace

// ---------------------------------------------------------------------------
extern "C" void kernel_launch(void* const* d_in, const int* in_sizes, int n_in,
                              void* d_out, int out_size, void* d_ws, size_t ws_size,
                              hipStream_t stream)
{
  (void)in_sizes; (void)n_in; (void)out_size; (void)ws_size;

  const float* s     = (const float*)d_in[0];
  const float* t2s   = (const float*)d_in[1];
  const float* w1    = (const float*)d_in[2];
  const float* w2    = (const float*)d_in[3];
  const float* w3    = (const float*)d_in[4];
  const float* gthr  = (const float*)d_in[5];
  const float* w000  = (const float*)d_in[6];
  const float* w220  = (const float*)d_in[7];
  const float* w022  = (const float*)d_in[8];
  const float* w202  = (const float*)d_in[9];
  const float* w222  = (const float*)d_in[10];
  const float* w2022 = (const float*)d_in[11];
  const float* w2202 = (const float*)d_in[12];
  const float* w2222 = (const float*)d_in[13];
  const float* csc   = (const float*)d_in[14];
  float* out = (float*)d_out;

  char* ws = (char*)d_ws;
  float* mixed_ws = (float*)(ws + MIX_WS_OFF);
  float* w202T    = (float*)(ws + W202T_OFF);
  float* wsym     = (float*)(ws + WSYM_OFF);
  float* w022T    = (float*)(ws + W022T_OFF);

  Coefs cf;
  {
    float c000v[1], c022v[25], c202v[25], c220v[25];
    w3j_host(0, 0, 0, c000v);
    w3j_host(0, 2, 2, c022v);
    w3j_host(2, 0, 2, c202v);
    w3j_host(2, 2, 0, c220v);
    w3j_host(2, 2, 2, cf.c222);
    for (int i = 0; i < 125; i++) cf.c222[i] *= C222_FLIP;
    for (int k = 0; k < 5; k++) {
      cf.d022[k] = c022v[k * 5 + k];
      cf.d202[k] = c202v[k * 5 + k];
      cf.d220[k] = c220v[k * 5 + k];
    }
    (void)c000v;
    cf.a0 = (float)std::sqrt(1.0 / (64.0 * 64.0 + 16.0 * 16.0));
    cf.a2 = (float)std::sqrt(5.0 / (2.0 * 64.0 * 16.0 + 16.0 * 16.0));
    cf.b2 = (float)std::sqrt(5.0 / (3.0 * 128.0 * 128.0));
  }

  hipLaunchKernelGGL(k_prep, dim3(512), dim3(256), 0, stream,
                     s, t2s, w1, w2, w3, gthr, mixed_ws);
  hipLaunchKernelGGL(k_wprep, dim3(256), dim3(256), 0, stream,
                     w000, wsym, w2202, w202T, w022, w022T);
  hipLaunchKernelGGL(k_fused, dim3(512), dim3(512), 0, stream,
                     s, t2s, mixed_ws, wsym, w220, w022T, w202, w222,
                     w2022, w202T, w2222, csc, out, cf);
}

// Round 10
// 687.986 us; speedup vs baseline: 2.6557x; 1.2088x over previous
//
#include <hip/hip_runtime.h>
#include <hip/hip_bf16.h>
#include <cmath>
#include <complex>
#include <vector>
#include <cstring>
#include <cstdint>

// ---------------------------------------------------------------------------
// ShieldingT2Model: round 10 — y000 moved to MFMA GEMM (split-bf16, 3-mfma).
// B=16384, NS=64, NK=32, NL=16, HM=256, HC=128, out = (B,5) f32.
//
// r7 2-batch weight reuse : 849 us, VALU 45%
// r9 interleaved-pair LDS : 831 us, VALU 37%  <- f32-VALU path plateaued;
//    MfmaUtil 0 all session. ~54K FMA-cyc/thread, 2.7x latency stall.
// r10: k_y0 = MFMA GEMM for y000 (M=16384,K=2080=65x32,N=128). A = pair
//    products built in LDS from s; B = Wsym^T packed chunk-major bf16 hi/lo.
//    Split-bf16 both sides, 3 MFMAs/frag => ~f32 accuracy. k_fused drops
//    y000 + gram-256 (y220 via 136 sym pairs + w220s), reads y0 from ws.
//
// MFMA layout facts (HW-verified per guide):
//   A-frag:  A[m=lane&15][k=(lane>>4)*8+j], 8 bf16 per lane
//   B-frag:  B^T rows, same per-lane form (B^T[n=lane&15][k=quad*8+j])
//   C/D   :  col=lane&15 (n), row=(lane>>4)*4+reg (m)
//
// ws (~10.5 MB): mixed@0 | w202T@327680 | w022T@393216 | w220s@917504 |
//                WsymT_h@987136 | WsymT_l@1519616 | y0@2052096
// C222 sign: majority-positive canonicalization, then flipped (r2/r3 A/B).
// ---------------------------------------------------------------------------

#define C222_FLIP -1.0f

#define MIX_WS_OFF   0
#define W202T_OFF    327680
#define W022T_OFF    393216
#define W220S_OFF    917504
#define WSYMH_OFF    987136
#define WSYML_OFF    1519616
#define Y0_WS_OFF    2052096

typedef __attribute__((ext_vector_type(8))) short short8;
typedef __attribute__((ext_vector_type(4))) float f32x4;

struct Coefs {
  float c222[125];   // full (2,2,2) real wigner-3j, [i][j][k]
  float d022[5];     // diag of C022[0,:,:]
  float d202[5];     // diag of C202[:,0,:]
  float d220[5];     // diag of C220[:,:,0]
  float a0, a2, b2;
};

#define FMA8(acc, wa, wb, sv) do { \
  acc[0] = fmaf((wa).x, (sv), acc[0]); \
  acc[1] = fmaf((wa).y, (sv), acc[1]); \
  acc[2] = fmaf((wa).z, (sv), acc[2]); \
  acc[3] = fmaf((wa).w, (sv), acc[3]); \
  acc[4] = fmaf((wb).x, (sv), acc[4]); \
  acc[5] = fmaf((wb).y, (sv), acc[5]); \
  acc[6] = fmaf((wb).z, (sv), acc[6]); \
  acc[7] = fmaf((wb).w, (sv), acc[7]); \
} while (0)

#define FMA4(acc, wa, sv) do { \
  acc[0] = fmaf((wa).x, (sv), acc[0]); \
  acc[1] = fmaf((wa).y, (sv), acc[1]); \
  acc[2] = fmaf((wa).z, (sv), acc[2]); \
  acc[3] = fmaf((wa).w, (sv), acc[3]); \
} while (0)

__device__ __forceinline__ float act_silu(float x) {
  return 1.679f * x / (1.0f + expf(-x));   // SILU_NORM * silu(x)
}

__device__ __forceinline__ short f2bf(float x) {
  __hip_bfloat16 h = __float2bfloat16(x);
  return *reinterpret_cast<short*>(&h);
}
__device__ __forceinline__ float bf2f(short s) {
  __hip_bfloat16 h = *reinterpret_cast<__hip_bfloat16*>(&s);
  return __bfloat162float(h);
}

// ---------------------------------------------------------------------------
// K1: MLP -> weights -> mixed.  32 b per wg, 256 threads. (proven, unchanged)
// ---------------------------------------------------------------------------
__global__ __launch_bounds__(256) void k_prep(
    const float* __restrict__ s, const float* __restrict__ t2s,
    const float* __restrict__ w1, const float* __restrict__ w2,
    const float* __restrict__ w3, const float* __restrict__ gthr,
    float* __restrict__ mixed_ws)
{
  __shared__ float sT[64][36];    // [k][b], padded
  __shared__ float hT[256][36];   // [c][b], holds h1 then h2

  const int tid = threadIdx.x;
  const int b0  = blockIdx.x * 32;

  #pragma unroll
  for (int i = 0; i < 8; i++) {
    int flat = tid + i * 256;
    int bl = flat >> 6, k = flat & 63;
    sT[k][bl] = s[(size_t)(b0 + bl) * 64 + k];
  }
  __syncthreads();

  const int cg = tid & 31, bg = tid >> 5;
  const int c0 = cg * 8, bb0 = bg * 4;

  float acc[4][8];
  #pragma unroll
  for (int j = 0; j < 4; j++)
    #pragma unroll
    for (int i = 0; i < 8; i++) acc[j][i] = 0.f;

  for (int k = 0; k < 64; k++) {
    float4 bv = *(const float4*)&sT[k][bb0];
    float4 wa = *(const float4*)&w1[k * 256 + c0];
    float4 wb = *(const float4*)&w1[k * 256 + c0 + 4];
    const float bvv[4] = {bv.x, bv.y, bv.z, bv.w};
    #pragma unroll
    for (int j = 0; j < 4; j++) { FMA8(acc[j], wa, wb, bvv[j]); }
  }
  #pragma unroll
  for (int j = 0; j < 4; j++)
    #pragma unroll
    for (int i = 0; i < 8; i++)
      hT[c0 + i][bb0 + j] = act_silu(acc[j][i] * 0.125f);
  __syncthreads();

  float acc2[4][8];
  #pragma unroll
  for (int j = 0; j < 4; j++)
    #pragma unroll
    for (int i = 0; i < 8; i++) acc2[j][i] = 0.f;

  for (int k = 0; k < 256; k++) {
    float4 bv = *(const float4*)&hT[k][bb0];
    float4 wa = *(const float4*)&w2[k * 256 + c0];
    float4 wb = *(const float4*)&w2[k * 256 + c0 + 4];
    const float bvv[4] = {bv.x, bv.y, bv.z, bv.w};
    #pragma unroll
    for (int j = 0; j < 4; j++) { FMA8(acc2[j], wa, wb, bvv[j]); }
  }
  __syncthreads();
  #pragma unroll
  for (int j = 0; j < 4; j++)
    #pragma unroll
    for (int i = 0; i < 8; i++)
      hT[c0 + i][bb0 + j] = act_silu(acc2[j][i] * 0.0625f);
  __syncthreads();

  const int jj  = tid & 31;
  const int blg = tid >> 5;
  float acc3[4] = {0.f, 0.f, 0.f, 0.f};
  for (int k = 0; k < 256; k++) {
    float wv  = w3[k * 32 + jj];
    float4 hv = *(const float4*)&hT[k][blg * 4];
    acc3[0] = fmaf(hv.x, wv, acc3[0]);
    acc3[1] = fmaf(hv.y, wv, acc3[1]);
    acc3[2] = fmaf(hv.z, wv, acc3[2]);
    acc3[3] = fmaf(hv.w, wv, acc3[3]);
  }
  const float thrv = gthr[jj];
  #pragma unroll
  for (int r = 0; r < 4; r++) {
    int bl = blg * 4 + r;
    int b  = b0 + bl;
    float rel = acc3[r] * 0.0625f;
    const float* tp = t2s + (size_t)(b * 32 + jj) * 5;
    float tv0 = tp[0], tv1 = tp[1], tv2 = tp[2], tv3 = tp[3], tv4 = tp[4];
    float mag  = sqrtf(tv0*tv0 + tv1*tv1 + tv2*tv2 + tv3*tv3 + tv4*tv4);
    float gate = mag / (mag + thrv);
    float w = rel * gate * 0.17677669529663687f;  // 1/sqrt(32)
    float pm0 = w*tv0, pm1 = w*tv1, pm2 = w*tv2, pm3 = w*tv3, pm4 = w*tv4;
    #pragma unroll
    for (int off = 16; off >= 1; off >>= 1) {
      pm0 += __shfl_xor(pm0, off);
      pm1 += __shfl_xor(pm1, off);
      pm2 += __shfl_xor(pm2, off);
      pm3 += __shfl_xor(pm3, off);
      pm4 += __shfl_xor(pm4, off);
    }
    if (jj == 0) {
      float* mp = mixed_ws + (size_t)b * 5;
      mp[0] = pm0; mp[1] = pm1; mp[2] = pm2; mp[3] = pm3; mp[4] = pm4;
    }
  }
}

// ---------------------------------------------------------------------------
// K2: merged weight prep.
//  blk 0..63   : WsymT bf16 hi/lo, packed chunk-major: off = ((p>>5)*128+w)*32+(p&31)
//  blk 64..127 : transpose tp2_w202 -> w202T
//  blk 128..255: transpose w022 -> w022T [v][u][w]
//  blk 256     : symmetrized w220 pairs -> w220s f32 [136][128]
// ---------------------------------------------------------------------------
__global__ __launch_bounds__(256) void k_wprep(
    const float* __restrict__ w000, short* __restrict__ Wh, short* __restrict__ Wl,
    const float* __restrict__ w2202, float* __restrict__ w202T,
    const float* __restrict__ w022, float* __restrict__ w022T,
    const float* __restrict__ w220, float* __restrict__ w220s)
{
  const int tid = threadIdx.x;
  const int blk = blockIdx.x;
  if (blk < 64) {
    int u = blk;
    int base = u * 64 - (u * (u - 1)) / 2;
    int n = (64 - u) * 128;
    for (int idx = tid; idx < n; idx += 256) {
      int t = idx >> 7, wc = idx & 127;
      int v = u + t;
      int p = base + t;
      float val = w000[(size_t)(u * 64 + v) * 128 + wc];
      if (v > u) val += w000[(size_t)(v * 64 + u) * 128 + wc];
      int off = ((p >> 5) * 128 + wc) * 32 + (p & 31);
      short hs = f2bf(val);
      Wh[off] = hs;
      Wl[off] = f2bf(val - bf2f(hs));
    }
  } else if (blk < 128) {
    int idx = (blk - 64) * 256 + tid;  // 16384
    int u = idx >> 7, v = idx & 127;
    w202T[v * 128 + u] = w2202[u * 128 + v];
  } else if (blk < 256) {
    int e0 = (blk - 128) * 1024;       // 128 blocks x 1024 = 131072
    #pragma unroll
    for (int i = 0; i < 4; i++) {
      int e = e0 + i * 256 + tid;
      int w = e & 127, r = e >> 7;     // r = u*16+v
      int u = r >> 4, v = r & 15;
      w022T[(size_t)(v * 64 + u) * 128 + w] = w022[e];
    }
  } else {
    // w220s: 136 pairs x 128
    for (int idx = tid; idx < 136 * 128; idx += 256) {
      int q = idx >> 7, wc = idx & 127;
      int u = 0;
      while ((u + 1) * 16 - ((u + 1) * u) / 2 <= q) u++;
      int base = u * 16 - (u * (u - 1)) / 2;
      int v = u + (q - base);
      float val = w220[(size_t)(u * 16 + v) * 128 + wc];
      if (v > u) val += w220[(size_t)(v * 16 + u) * 128 + wc];
      w220s[(size_t)q * 128 + wc] = val;
    }
  }
}

// ---------------------------------------------------------------------------
// K_y0: MFMA GEMM  Y0raw[b][w] = sum_p P[b][p] Wsym[p][w],  K=2080=65x32.
// 256 blocks x 256 threads (4 waves). Block: 64 batches x 128 channels.
// Split-bf16 both operands, 3 MFMAs (hh, hl, lh); residual ~2^-18.
// ---------------------------------------------------------------------------
__global__ __launch_bounds__(256) void k_y0(
    const float* __restrict__ s,
    const short* __restrict__ Wh, const short* __restrict__ Wl,
    float* __restrict__ y0w)
{
  __shared__ float sL[64][64];                     // 16384 B
  __shared__ unsigned short p16[2080];             //  4160 B
  __shared__ __align__(16) short AhL[2048];        //  4096 B  [64 b][32 k]
  __shared__ __align__(16) short AlL[2048];        //  4096 B
  __shared__ __align__(16) short BhL[4096];        //  8192 B  [128 w][32 k]
  __shared__ __align__(16) short BlL[4096];        //  8192 B
  // total ~44 KB

  const int tid  = threadIdx.x;
  const int b0   = blockIdx.x * 64;
  const int wave = tid >> 6;
  const int lane = tid & 63;
  const int m16  = lane & 15;
  const int quad = lane >> 4;

  // stage s (4096 floats)
  for (int idx = tid; idx < 4096; idx += 256) {
    int bl = idx >> 6, k = idx & 63;
    sL[bl][k] = s[(size_t)(b0 + bl) * 64 + k];
  }
  if (tid < 64) {  // pair table p -> (u<<8)|v  (same as proven r7 code)
    int u = tid;
    int base = u * 64 - (u * (u - 1)) / 2;
    for (int t = 0; t < 64 - u; t++)
      p16[base + t] = (unsigned short)((u << 8) | (u + t));
  }
  __syncthreads();

  f32x4 acc[8];
  #pragma unroll
  for (int nb = 0; nb < 8; nb++) acc[nb] = 0.f;

  for (int c = 0; c < 65; c++) {
    // stage A: 2048 pair products, split hi/lo
    #pragma unroll
    for (int i = 0; i < 8; i++) {
      int e = tid + i * 256;
      int bl = e >> 5, kk = e & 31;
      int uv = p16[c * 32 + kk];
      float x = sL[bl][uv >> 8] * sL[bl][uv & 255];
      short hs = f2bf(x);
      AhL[e] = hs;
      AlL[e] = f2bf(x - bf2f(hs));
    }
    // stage B: 4096 shorts per split, fully coalesced (chunk-major packing)
    {
      const short8* gh = (const short8*)(Wh + (size_t)c * 4096);
      const short8* gl = (const short8*)(Wl + (size_t)c * 4096);
      ((short8*)BhL)[tid]       = gh[tid];
      ((short8*)BhL)[tid + 256] = gh[tid + 256];
      ((short8*)BlL)[tid]       = gl[tid];
      ((short8*)BlL)[tid + 256] = gl[tid + 256];
    }
    __syncthreads();

    short8 ah = *(const short8*)&AhL[(wave * 16 + m16) * 32 + quad * 8];
    short8 al = *(const short8*)&AlL[(wave * 16 + m16) * 32 + quad * 8];
    #pragma unroll
    for (int nb = 0; nb < 8; nb++) {
      short8 bh = *(const short8*)&BhL[(nb * 16 + m16) * 32 + quad * 8];
      short8 bl = *(const short8*)&BlL[(nb * 16 + m16) * 32 + quad * 8];
      acc[nb] = __builtin_amdgcn_mfma_f32_16x16x32_bf16(ah, bh, acc[nb], 0, 0, 0);
      acc[nb] = __builtin_amdgcn_mfma_f32_16x16x32_bf16(ah, bl, acc[nb], 0, 0, 0);
      acc[nb] = __builtin_amdgcn_mfma_f32_16x16x32_bf16(al, bh, acc[nb], 0, 0, 0);
    }
    __syncthreads();  // frag reads done before next chunk's staging writes
  }

  // epilogue: D row=(quad*4+r)=batch-local, col=lane&15=channel-local
  #pragma unroll
  for (int nb = 0; nb < 8; nb++) {
    #pragma unroll
    for (int r = 0; r < 4; r++) {
      int b  = b0 + wave * 16 + quad * 4 + r;
      int ch = nb * 16 + m16;
      y0w[(size_t)b * 128 + ch] = acc[nb][r];   // raw sum; a0 applied later
    }
  }
}

// ---------------------------------------------------------------------------
// K3: fused heavy kernel (r9 minus y000/gram-256; y0 partial from ws,
// y220 via 136 symmetric pairs). 32 b per block, 512 blocks, 512 threads.
// ---------------------------------------------------------------------------
__global__ __launch_bounds__(512, 4) void k_fused(
    const float* __restrict__ s, const float* __restrict__ t2s,
    const float* __restrict__ mixed_ws,
    const float* __restrict__ y0w,   const float* __restrict__ w220s,
    const float* __restrict__ w022T, const float* __restrict__ w202,
    const float* __restrict__ w222,
    const float* __restrict__ w2022, const float* __restrict__ w202T,
    const float* __restrict__ w2222,
    const float* __restrict__ csc, float* __restrict__ out, Coefs cf)
{
  __shared__ __align__(16) float sI[16][64][2];    //  8192 B
  __shared__ __align__(16) float tI[16][16][5][2]; // 10240 B
  __shared__ __align__(16) float y0I[16][128][2];  // 16384 B
  __shared__ float cL222[125];                     //   500 B
  __shared__ float corrAcc[32][5];                 //   640 B
  __shared__ float pPL[32][25];                    //  3200 B
  __shared__ unsigned char p136[136];              //   136 B
  __shared__ __align__(16) char uni[17408];        // union (time-disjoint):
  //   y220 : grI  = float[16][136][2] (17408 B) @ uni
  //   tp222: GI = float[16][25][2] (3200) @ uni ; QI = float[16][16][5][2] @+3200
  //   ph5  : y2iI = float[16][128][2] (16384 B) @ uni
  float (*grI)[136][2]   = (float(*)[136][2])uni;
  float (*GI)[25][2]     = (float(*)[25][2])uni;
  float (*QI)[16][5][2]  = (float(*)[16][5][2])(uni + 3200);
  float (*y2iI)[128][2]  = (float(*)[128][2])uni;
  // total ~56 KB -> 2 blocks/CU

  const int tid = threadIdx.x;
  const int b0  = blockIdx.x * 32;

  float dk022[5], dk202[5], dk220[5];
  #pragma unroll
  for (int k = 0; k < 5; k++) {
    dk022[k] = cf.d022[k]; dk202[k] = cf.d202[k]; dk220[k] = cf.d220[k];
  }

  // ---- stage (interleaved pair layouts) ----
  if (tid == 0) {
    #pragma unroll
    for (int i = 0; i < 125; i++) cL222[i] = cf.c222[i];
  }
  for (int idx = tid; idx < 32 * 64; idx += 512) {
    int bl = idx >> 6, k = idx & 63;
    sI[bl >> 1][k][bl & 1] = s[(size_t)(b0 + bl) * 64 + k];
  }
  for (int idx = tid; idx < 32 * 80; idx += 512) {
    int bl = idx / 80, rem = idx - bl * 80;
    int u = rem / 5, m = rem - u * 5;
    int b = b0 + bl;
    float v;
    if (u < 15) v = t2s[(size_t)(b * 32 + u) * 5 + m];
    else {
      v = 0.f;
      for (int kk = 0; kk < 32; kk++) v += t2s[(size_t)(b * 32 + kk) * 5 + m];
    }
    tI[bl >> 1][u][m][bl & 1] = v;
  }
  if (tid < 16) {  // 136-pair table: (u<<4)|v
    int u = tid;
    int base = u * 16 - (u * (u - 1)) / 2;
    for (int t = 0; t < 16 - u; t++)
      p136[base + t] = (unsigned char)((u << 4) | (u + t));
  }
  __syncthreads();

  // gram for 136 sym pairs -> grI
  for (int idx = tid; idx < 4352; idx += 512) {
    int g_ = idx / 272, rem = idx - g_ * 272;
    int q = rem >> 1, h = rem & 1;
    int uv = p136[q];
    int u = uv >> 4, v = uv & 15;
    float gg = 0.f;
    #pragma unroll
    for (int m = 0; m < 5; m++)
      gg = fmaf(dk220[m] * tI[g_][u][m][h], tI[g_][v][m][h], gg);
    grI[g_][q][h] = gg;
  }
  __syncthreads();

  const int xw = tid & 31;
  const int g  = tid >> 5;
  const int w0 = xw * 4;
  const int bA = 2 * g, bB = 2 * g + 1;

  // ---- y0: partial from ws (y000 GEMM) + y220 (136 sym pairs) ----
  float y0a[2][4];
  {
    float4 ta = *(const float4*)(y0w + (size_t)(b0 + bA) * 128 + w0);
    float4 tb = *(const float4*)(y0w + (size_t)(b0 + bB) * 128 + w0);
    y0a[0][0] = ta.x; y0a[0][1] = ta.y; y0a[0][2] = ta.z; y0a[0][3] = ta.w;
    y0a[1][0] = tb.x; y0a[1][1] = tb.y; y0a[1][2] = tb.z; y0a[1][3] = tb.w;
  }
  #pragma unroll 8
  for (int q = 0; q < 136; q++) {
    float2 gr = *(const float2*)&grI[g][q][0];
    float4 w4 = *(const float4*)(w220s + (size_t)q * 128 + w0);
    FMA4(y0a[0], w4, gr.x);
    FMA4(y0a[1], w4, gr.y);
  }
  #pragma unroll
  for (int wi = 0; wi < 4; wi++) {
    float2 o; o.x = cf.a0 * y0a[0][wi]; o.y = cf.a0 * y0a[1][wi];
    *(float2*)&y0I[g][w0 + wi][0] = o;
  }
  __syncthreads();  // grI dead; y0I published

  // ---- y2 (registers, both batches) ----
  float y2acc[5][2][4];
  #pragma unroll
  for (int k = 0; k < 5; k++)
    #pragma unroll
    for (int r = 0; r < 2; r++)
      #pragma unroll
      for (int wi = 0; wi < 4; wi++) y2acc[k][r][wi] = 0.f;

  // tp022 (w022T: [v][u][w] contiguous; 1 ds_read_b64/iter)
  for (int v = 0; v < 16; v++) {
    float a4[2][4] = {{0.f,0.f,0.f,0.f},{0.f,0.f,0.f,0.f}};
    #pragma unroll 8
    for (int u = 0; u < 64; u++) {
      float2 su = *(const float2*)&sI[g][u][0];
      float4 w4 = *(const float4*)(w022T + (size_t)(v * 64 + u) * 128 + w0);
      FMA4(a4[0], w4, su.x);
      FMA4(a4[1], w4, su.y);
    }
    #pragma unroll
    for (int k = 0; k < 5; k++) {
      float2 tv = *(const float2*)&tI[g][v][k][0];
      float fa = dk022[k] * tv.x;
      float fb = dk022[k] * tv.y;
      #pragma unroll
      for (int wi = 0; wi < 4; wi++) {
        y2acc[k][0][wi] = fmaf(fa, a4[0][wi], y2acc[k][0][wi]);
        y2acc[k][1][wi] = fmaf(fb, a4[1][wi], y2acc[k][1][wi]);
      }
    }
  }
  // tp202 (original w202 [u][v][w], contiguous in v)
  for (int u = 0; u < 16; u++) {
    float a4[2][4] = {{0.f,0.f,0.f,0.f},{0.f,0.f,0.f,0.f}};
    #pragma unroll 8
    for (int v = 0; v < 64; v++) {
      float2 sv = *(const float2*)&sI[g][v][0];
      float4 w4 = *(const float4*)(w202 + (size_t)(u * 64 + v) * 128 + w0);
      FMA4(a4[0], w4, sv.x);
      FMA4(a4[1], w4, sv.y);
    }
    #pragma unroll
    for (int k = 0; k < 5; k++) {
      float2 tu = *(const float2*)&tI[g][u][k][0];
      float fa = dk202[k] * tu.x;
      float fb = dk202[k] * tu.y;
      #pragma unroll
      for (int wi = 0; wi < 4; wi++) {
        y2acc[k][0][wi] = fmaf(fa, a4[0][wi], y2acc[k][0][wi]);
        y2acc[k][1][wi] = fmaf(fb, a4[1][wi], y2acc[k][1][wi]);
      }
    }
  }
  // tp222
  for (int u = 0; u < 16; u++) {
    // G staging: 16 g x 25 jk x 2 h = 800 elements
    for (int idx = tid; idx < 800; idx += 512) {
      int g_ = idx / 50, rem = idx - g_ * 50;
      int jk = rem >> 1, h = rem & 1;
      float gg = 0.f;
      #pragma unroll
      for (int ii = 0; ii < 5; ii++)
        gg = fmaf(cL222[ii * 25 + jk], tI[g_][u][ii][h], gg);
      GI[g_][jk][h] = gg;
    }
    __syncthreads();
    for (int idx = tid; idx < 2560; idx += 512) {
      int g_ = idx / 160, rem = idx - g_ * 160;
      int vv = rem / 10, r2 = rem - vv * 10;
      int kk = r2 >> 1, h = r2 & 1;
      float q = 0.f;
      #pragma unroll
      for (int jj = 0; jj < 5; jj++)
        q = fmaf(GI[g_][jj * 5 + kk][h], tI[g_][vv][jj][h], q);
      QI[g_][vv][kk][h] = q;
    }
    __syncthreads();
    #pragma unroll 4
    for (int v = 0; v < 16; v++) {
      float4 w4 = *(const float4*)(w222 + (size_t)(u * 16 + v) * 128 + w0);
      #pragma unroll
      for (int k = 0; k < 5; k++) {
        float2 q2 = *(const float2*)&QI[g][v][k][0];
        FMA4(y2acc[k][0], w4, q2.x);
        FMA4(y2acc[k][1], w4, q2.y);
      }
    }
    __syncthreads();   // QI reads done
  }
  // scale y2 in registers
  #pragma unroll
  for (int k = 0; k < 5; k++)
    #pragma unroll
    for (int r = 0; r < 2; r++)
      #pragma unroll
      for (int wi = 0; wi < 4; wi++) y2acc[k][r][wi] *= cf.a2;

  // ================= phase 5: tp2, register y2, paired LDS =================
  // 022 path
  {
    float gvr[2][4] = {{0.f,0.f,0.f,0.f},{0.f,0.f,0.f,0.f}};
    #pragma unroll 8
    for (int u = 0; u < 128; u++) {
      float2 y0p = *(const float2*)&y0I[g][u][0];
      float4 w4 = *(const float4*)(w2022 + (size_t)u * 128 + w0);
      FMA4(gvr[0], w4, y0p.x);
      FMA4(gvr[1], w4, y0p.y);
    }
    #pragma unroll
    for (int k = 0; k < 5; k++) {
      float pA = gvr[0][0]*y2acc[k][0][0] + gvr[0][1]*y2acc[k][0][1]
               + gvr[0][2]*y2acc[k][0][2] + gvr[0][3]*y2acc[k][0][3];
      float pB = gvr[1][0]*y2acc[k][1][0] + gvr[1][1]*y2acc[k][1][1]
               + gvr[1][2]*y2acc[k][1][2] + gvr[1][3]*y2acc[k][1][3];
      pA += __shfl_xor(pA, 16); pA += __shfl_xor(pA, 8); pA += __shfl_xor(pA, 4);
      pA += __shfl_xor(pA, 2);  pA += __shfl_xor(pA, 1);
      pB += __shfl_xor(pB, 16); pB += __shfl_xor(pB, 8); pB += __shfl_xor(pB, 4);
      pB += __shfl_xor(pB, 2);  pB += __shfl_xor(pB, 1);
      if (xw == 0) {
        corrAcc[bA][k] = dk022[k] * pA;
        corrAcc[bB][k] = dk022[k] * pB;
      }
    }
  }
  // 202 path
  {
    float hvr[2][4] = {{0.f,0.f,0.f,0.f},{0.f,0.f,0.f,0.f}};
    #pragma unroll 8
    for (int v = 0; v < 128; v++) {
      float2 y0p = *(const float2*)&y0I[g][v][0];
      float4 w4 = *(const float4*)(w202T + (size_t)v * 128 + w0);
      FMA4(hvr[0], w4, y0p.x);
      FMA4(hvr[1], w4, y0p.y);
    }
    #pragma unroll
    for (int k = 0; k < 5; k++) {
      float pA = hvr[0][0]*y2acc[k][0][0] + hvr[0][1]*y2acc[k][0][1]
               + hvr[0][2]*y2acc[k][0][2] + hvr[0][3]*y2acc[k][0][3];
      float pB = hvr[1][0]*y2acc[k][1][0] + hvr[1][1]*y2acc[k][1][1]
               + hvr[1][2]*y2acc[k][1][2] + hvr[1][3]*y2acc[k][1][3];
      pA += __shfl_xor(pA, 16); pA += __shfl_xor(pA, 8); pA += __shfl_xor(pA, 4);
      pA += __shfl_xor(pA, 2);  pA += __shfl_xor(pA, 1);
      pB += __shfl_xor(pB, 16); pB += __shfl_xor(pB, 8); pB += __shfl_xor(pB, 4);
      pB += __shfl_xor(pB, 2);  pB += __shfl_xor(pB, 1);
      if (xw == 0) {
        corrAcc[bA][k] += dk202[k] * pA;
        corrAcc[bB][k] += dk202[k] * pB;
      }
    }
  }
  // 222 path
  for (int i = 0; i < 5; i++) {
    #pragma unroll
    for (int wi = 0; wi < 4; wi++) {
      float2 o; o.x = y2acc[i][0][wi]; o.y = y2acc[i][1][wi];
      *(float2*)&y2iI[g][w0 + wi][0] = o;
    }
    __syncthreads();
    float zr[2][4] = {{0.f,0.f,0.f,0.f},{0.f,0.f,0.f,0.f}};
    #pragma unroll 8
    for (int u = 0; u < 128; u++) {
      float2 yp = *(const float2*)&y2iI[g][u][0];
      float4 w4 = *(const float4*)(w2222 + (size_t)u * 128 + w0);
      FMA4(zr[0], w4, yp.x);
      FMA4(zr[1], w4, yp.y);
    }
    #pragma unroll
    for (int j = 0; j < 5; j++) {
      float pA = zr[0][0]*y2acc[j][0][0] + zr[0][1]*y2acc[j][0][1]
               + zr[0][2]*y2acc[j][0][2] + zr[0][3]*y2acc[j][0][3];
      float pB = zr[1][0]*y2acc[j][1][0] + zr[1][1]*y2acc[j][1][1]
               + zr[1][2]*y2acc[j][1][2] + zr[1][3]*y2acc[j][1][3];
      pA += __shfl_xor(pA, 16); pA += __shfl_xor(pA, 8); pA += __shfl_xor(pA, 4);
      pA += __shfl_xor(pA, 2);  pA += __shfl_xor(pA, 1);
      pB += __shfl_xor(pB, 16); pB += __shfl_xor(pB, 8); pB += __shfl_xor(pB, 4);
      pB += __shfl_xor(pB, 2);  pB += __shfl_xor(pB, 1);
      if (xw == 0) {
        pPL[bA][i * 5 + j] = pA;
        pPL[bB][i * 5 + j] = pB;
      }
    }
    __syncthreads();   // y2iI reads done before next i's overwrite
  }

  // ---- epilogue ----
  if (tid < 160) {
    int bb = tid / 5, k = tid - bb * 5;
    float c2 = 0.f;
    #pragma unroll
    for (int ii = 0; ii < 5; ii++)
      #pragma unroll
      for (int jj = 0; jj < 5; jj++)
        c2 = fmaf(cL222[ii * 25 + jj * 5 + k], pPL[bb][ii * 5 + jj], c2);
    float tot = corrAcc[bb][k] + c2;
    int b = b0 + bb;
    out[(size_t)b * 5 + k] = mixed_ws[(size_t)b * 5 + k] + csc[0] * cf.b2 * tot;
  }
}

// ---------------------------------------------------------------------------
// Host: replicate reference's wigner-3j computation (RREF null space).
// ---------------------------------------------------------------------------
namespace {

using cplx = std::complex<double>;

static void su2_gen(int l, std::vector<cplx>& Jx, std::vector<cplx>& Jy,
                    std::vector<cplx>& Jz) {
  int d = 2 * l + 1;
  Jx.assign((size_t)d * d, cplx(0, 0));
  Jy.assign((size_t)d * d, cplx(0, 0));
  Jz.assign((size_t)d * d, cplx(0, 0));
  for (int a = 0; a < d; a++) Jz[(size_t)a * d + a] = cplx(a - l, 0);
  for (int r = 1; r < d; r++) {
    double m = (r - 1) - l;
    double v = std::sqrt(l * (l + 1.0) - m * (m + 1.0));
    Jx[(size_t)r * d + (r - 1)] += cplx(v / 2, 0);
    Jx[(size_t)(r - 1) * d + r] += cplx(v / 2, 0);
    Jy[(size_t)r * d + (r - 1)] += cplx(0, -v / 2);
    Jy[(size_t)(r - 1) * d + r] += cplx(0, v / 2);
  }
}

static void real_basis(int l, std::vector<cplx>& U) {
  int d = 2 * l + 1;
  U.assign((size_t)d * d, cplx(0, 0));
  U[(size_t)l * d + l] = cplx(1, 0);
  double is2 = 1.0 / std::sqrt(2.0);
  for (int m = 1; m <= l; m++) {
    double sgn = (m % 2 == 0) ? 1.0 : -1.0;
    U[(size_t)(l + m) * d + (l + m)] = cplx(sgn * is2, 0);
    U[(size_t)(l + m) * d + (l - m)] = cplx(is2, 0);
    U[(size_t)(l - m) * d + (l - m)] = cplx(0, is2);
    U[(size_t)(l - m) * d + (l + m)] = cplx(0, -sgn * is2);
  }
}

static void real_gens(int l, std::vector<double> G[3]) {
  int d = 2 * l + 1;
  if (l == 0) { for (int a = 0; a < 3; a++) G[a].assign(1, 0.0); return; }
  std::vector<cplx> J[3];
  su2_gen(l, J[0], J[1], J[2]);
  std::vector<cplx> U;
  real_basis(l, U);
  for (int a = 0; a < 3; a++) {
    std::vector<cplx> T((size_t)d * d, cplx(0, 0));
    for (int i = 0; i < d; i++)
      for (int k = 0; k < d; k++) {
        cplx s(0, 0);
        for (int j = 0; j < d; j++)
          s += U[(size_t)i * d + j] * (cplx(0, -1) * J[a][(size_t)j * d + k]);
        T[(size_t)i * d + k] = s;
      }
    G[a].assign((size_t)d * d, 0.0);
    for (int i = 0; i < d; i++)
      for (int k = 0; k < d; k++) {
        cplx s(0, 0);
        for (int j = 0; j < d; j++)
          s += T[(size_t)i * d + j] * std::conj(U[(size_t)k * d + j]);
        G[a][(size_t)i * d + k] = s.real();
      }
  }
}

static void w3j_host(int l1, int l2, int l3, float* out) {
  int d1 = 2 * l1 + 1, d2 = 2 * l2 + 1, d3 = 2 * l3 + 1;
  int D = d1 * d2 * d3;
  std::vector<double> G1[3], G2[3], G3[3];
  real_gens(l1, G1); real_gens(l2, G2); real_gens(l3, G3);
  int R = 3 * D;
  std::vector<double> M((size_t)R * D, 0.0);
  for (int a = 0; a < 3; a++) {
    double* Ma = &M[(size_t)a * D * D];
    for (int i1 = 0; i1 < d1; i1++)
      for (int j1 = 0; j1 < d1; j1++) {
        double g = G1[a][(size_t)i1 * d1 + j1];
        if (g == 0.0) continue;
        for (int i2 = 0; i2 < d2; i2++)
          for (int i3 = 0; i3 < d3; i3++)
            Ma[(size_t)((i1 * d2 + i2) * d3 + i3) * D + ((j1 * d2 + i2) * d3 + i3)] += g;
      }
    for (int i2 = 0; i2 < d2; i2++)
      for (int j2 = 0; j2 < d2; j2++) {
        double g = G2[a][(size_t)i2 * d2 + j2];
        if (g == 0.0) continue;
        for (int i1 = 0; i1 < d1; i1++)
          for (int i3 = 0; i3 < d3; i3++)
            Ma[(size_t)((i1 * d2 + i2) * d3 + i3) * D + ((i1 * d2 + j2) * d3 + i3)] += g;
      }
    for (int i3 = 0; i3 < d3; i3++)
      for (int j3 = 0; j3 < d3; j3++) {
        double g = G3[a][(size_t)i3 * d3 + j3];
        if (g == 0.0) continue;
        for (int i1 = 0; i1 < d1; i1++)
          for (int i2 = 0; i2 < d2; i2++)
            Ma[(size_t)((i1 * d2 + i2) * d3 + i3) * D + ((i1 * d2 + i2) * d3 + j3)] += g;
      }
  }
  std::vector<int> pivcol;
  int rank = 0;
  for (int col = 0; col < D && rank < R; col++) {
    int pr = -1; double pv = 1e-9;
    for (int r = rank; r < R; r++) {
      double av = std::fabs(M[(size_t)r * D + col]);
      if (av > pv) { pv = av; pr = r; }
    }
    if (pr < 0) continue;
    if (pr != rank)
      for (int c = 0; c < D; c++) std::swap(M[(size_t)pr * D + c], M[(size_t)rank * D + c]);
    double inv = 1.0 / M[(size_t)rank * D + col];
    for (int c = 0; c < D; c++) M[(size_t)rank * D + c] *= inv;
    for (int r = 0; r < R; r++) {
      if (r == rank) continue;
      double f = M[(size_t)r * D + col];
      if (f != 0.0)
        for (int c = 0; c < D; c++) M[(size_t)r * D + c] -= f * M[(size_t)rank * D + c];
    }
    pivcol.push_back(col);
    rank++;
  }
  std::vector<char> isp(D, 0);
  for (int c : pivcol) isp[c] = 1;
  int fc = 0;
  for (int c = 0; c < D; c++) if (!isp[c]) { fc = c; break; }
  std::vector<double> x(D, 0.0);
  x[fc] = 1.0;
  for (int r = 0; r < rank; r++) x[pivcol[r]] = -M[(size_t)r * D + fc];
  double n = 0;
  for (double v : x) n += v * v;
  n = std::sqrt(n);
  for (int c = 0; c < D; c++) x[c] /= n;
  double best = 0;
  for (int c = 0; c < D; c++) { double av = std::fabs(x[c]); if (av > best) best = av; }
  double ssum = 0;
  for (int c = 0; c < D; c++) {
    double av = std::fabs(x[c]);
    if (av >= best * 0.999) ssum += (x[c] >= 0 ? 1.0 : -1.0);
  }
  double sgn = (ssum >= 0) ? 1.0 : -1.0;
  for (int c = 0; c < D; c++) out[c] = (float)(x[c] * sgn);
}

}  // namespace

// ---------------------------------------------------------------------------
extern "C" void kernel_launch(void* const* d_in, const int* in_sizes, int n_in,
                              void* d_out, int out_size, void* d_ws, size_t ws_size,
                              hipStream_t stream)
{
  (void)in_sizes; (void)n_in; (void)out_size; (void)ws_size;

  const float* s     = (const float*)d_in[0];
  const float* t2s   = (const float*)d_in[1];
  const float* w1    = (const float*)d_in[2];
  const float* w2    = (const float*)d_in[3];
  const float* w3    = (const float*)d_in[4];
  const float* gthr  = (const float*)d_in[5];
  const float* w000  = (const float*)d_in[6];
  const float* w220  = (const float*)d_in[7];
  const float* w022  = (const float*)d_in[8];
  const float* w202  = (const float*)d_in[9];
  const float* w222  = (const float*)d_in[10];
  const float* w2022 = (const float*)d_in[11];
  const float* w2202 = (const float*)d_in[12];
  const float* w2222 = (const float*)d_in[13];
  const float* csc   = (const float*)d_in[14];
  float* out = (float*)d_out;

  char* ws = (char*)d_ws;
  float* mixed_ws = (float*)(ws + MIX_WS_OFF);
  float* w202T    = (float*)(ws + W202T_OFF);
  float* w022T    = (float*)(ws + W022T_OFF);
  float* w220s    = (float*)(ws + W220S_OFF);
  short* WsymH    = (short*)(ws + WSYMH_OFF);
  short* WsymL    = (short*)(ws + WSYML_OFF);
  float* y0_ws    = (float*)(ws + Y0_WS_OFF);

  Coefs cf;
  {
    float c000v[1], c022v[25], c202v[25], c220v[25];
    w3j_host(0, 0, 0, c000v);
    w3j_host(0, 2, 2, c022v);
    w3j_host(2, 0, 2, c202v);
    w3j_host(2, 2, 0, c220v);
    w3j_host(2, 2, 2, cf.c222);
    for (int i = 0; i < 125; i++) cf.c222[i] *= C222_FLIP;
    for (int k = 0; k < 5; k++) {
      cf.d022[k] = c022v[k * 5 + k];
      cf.d202[k] = c202v[k * 5 + k];
      cf.d220[k] = c220v[k * 5 + k];
    }
    (void)c000v;
    cf.a0 = (float)std::sqrt(1.0 / (64.0 * 64.0 + 16.0 * 16.0));
    cf.a2 = (float)std::sqrt(5.0 / (2.0 * 64.0 * 16.0 + 16.0 * 16.0));
    cf.b2 = (float)std::sqrt(5.0 / (3.0 * 128.0 * 128.0));
  }

  hipLaunchKernelGGL(k_prep, dim3(512), dim3(256), 0, stream,
                     s, t2s, w1, w2, w3, gthr, mixed_ws);
  hipLaunchKernelGGL(k_wprep, dim3(257), dim3(256), 0, stream,
                     w000, WsymH, WsymL, w2202, w202T, w022, w022T, w220, w220s);
  hipLaunchKernelGGL(k_y0, dim3(256), dim3(256), 0, stream,
                     s, WsymH, WsymL, y0_ws);
  hipLaunchKernelGGL(k_fused, dim3(512), dim3(512), 0, stream,
                     s, t2s, mixed_ws, y0_ws, w220s, w022T, w202, w222,
                     w2022, w202T, w2222, csc, out, cf);
}

// Round 12
// 549.137 us; speedup vs baseline: 3.3272x; 1.2528x over previous
//
#include <hip/hip_runtime.h>
#include <hip/hip_bf16.h>
#include <cmath>
#include <complex>
#include <vector>
#include <cstring>
#include <cstdint>

// ---------------------------------------------------------------------------
// ShieldingT2Model: round 12 — r11 with corrected K-segmentation in k_y2.
// B=16384, NS=64, NK=32, NL=16, HM=256, HC=128, out = (B,5) f32.
//
// r10 y000 -> MFMA (k_y0) : 688 us (passed, absmax bit-identical)
// r11 full y-stage MFMA   : FAILED — 022/202 segments sized 64 chunks each
//     but K=16x64=1024=32 chunks: v=c>>1 ran 0..31 (NL=16!) -> OOB weight
//     reads in k_wprep + OOB tL reads in k_y2 -> absmax 3.22.
// r12: segmentation fixed: 022 c[0,32), 202 c[32,64), 222 c[64,72),
//     220 c[72,77). 77 chunks total. Nothing else changed.
//
// MFMA layout facts (HW-verified, k_y0 r10 passed bit-identical):
//   A-frag:  A[m=lane&15][k=(lane>>4)*8+j];  B-frag: B^T[n=lane&15][k=...]
//   C/D   :  col=lane&15 (n), row=(lane>>4)*4+reg (m)
//
// ws (~32.1 MB):
//   mixed @0 (327680) | w202T @327680 (65536) | WsymH @393216 (532480) |
//   WsymL @925696 (532480) | B2h @1458176 (630784) | B2l @2088960 (630784) |
//   y0 @2719744 (8388608) | y2p(bf16) @11108352 (20971520) -> 32079872
// C222 sign: majority-positive canonicalization, then flipped (r2/r3 A/B).
// ---------------------------------------------------------------------------

#define C222_FLIP -1.0f

#define MIX_WS_OFF   0
#define W202T_OFF    327680
#define WSYMH_OFF    393216
#define WSYML_OFF    925696
#define B2H_OFF      1458176
#define B2L_OFF      2088960
#define Y0_WS_OFF    2719744
#define Y2P_OFF      11108352

#define NCHUNK2      77

typedef __attribute__((ext_vector_type(8))) short short8;
typedef __attribute__((ext_vector_type(4))) float f32x4;

struct Coefs {
  float c222[125];   // full (2,2,2) real wigner-3j, [i][j][k]
  float d022[5];     // diag of C022[0,:,:]
  float d202[5];     // diag of C202[:,0,:]
  float d220[5];     // diag of C220[:,:,0]
  float a0, a2, b2;
};

#define FMA8(acc, wa, wb, sv) do { \
  acc[0] = fmaf((wa).x, (sv), acc[0]); \
  acc[1] = fmaf((wa).y, (sv), acc[1]); \
  acc[2] = fmaf((wa).z, (sv), acc[2]); \
  acc[3] = fmaf((wa).w, (sv), acc[3]); \
  acc[4] = fmaf((wb).x, (sv), acc[4]); \
  acc[5] = fmaf((wb).y, (sv), acc[5]); \
  acc[6] = fmaf((wb).z, (sv), acc[6]); \
  acc[7] = fmaf((wb).w, (sv), acc[7]); \
} while (0)

#define FMA4(acc, wa, sv) do { \
  acc[0] = fmaf((wa).x, (sv), acc[0]); \
  acc[1] = fmaf((wa).y, (sv), acc[1]); \
  acc[2] = fmaf((wa).z, (sv), acc[2]); \
  acc[3] = fmaf((wa).w, (sv), acc[3]); \
} while (0)

__device__ __forceinline__ float act_silu(float x) {
  return 1.679f * x / (1.0f + expf(-x));   // SILU_NORM * silu(x)
}

__device__ __forceinline__ short f2bf(float x) {
  __hip_bfloat16 h = __float2bfloat16(x);
  return *reinterpret_cast<short*>(&h);
}
__device__ __forceinline__ float bf2f(short s) {
  __hip_bfloat16 h = *reinterpret_cast<__hip_bfloat16*>(&s);
  return __bfloat162float(h);
}

// ---------------------------------------------------------------------------
// K1: MLP -> weights -> mixed.  32 b per wg, 256 threads. (proven, unchanged)
// ---------------------------------------------------------------------------
__global__ __launch_bounds__(256) void k_prep(
    const float* __restrict__ s, const float* __restrict__ t2s,
    const float* __restrict__ w1, const float* __restrict__ w2,
    const float* __restrict__ w3, const float* __restrict__ gthr,
    float* __restrict__ mixed_ws)
{
  __shared__ float sT[64][36];    // [k][b], padded
  __shared__ float hT[256][36];   // [c][b], holds h1 then h2

  const int tid = threadIdx.x;
  const int b0  = blockIdx.x * 32;

  #pragma unroll
  for (int i = 0; i < 8; i++) {
    int flat = tid + i * 256;
    int bl = flat >> 6, k = flat & 63;
    sT[k][bl] = s[(size_t)(b0 + bl) * 64 + k];
  }
  __syncthreads();

  const int cg = tid & 31, bg = tid >> 5;
  const int c0 = cg * 8, bb0 = bg * 4;

  float acc[4][8];
  #pragma unroll
  for (int j = 0; j < 4; j++)
    #pragma unroll
    for (int i = 0; i < 8; i++) acc[j][i] = 0.f;

  for (int k = 0; k < 64; k++) {
    float4 bv = *(const float4*)&sT[k][bb0];
    float4 wa = *(const float4*)&w1[k * 256 + c0];
    float4 wb = *(const float4*)&w1[k * 256 + c0 + 4];
    const float bvv[4] = {bv.x, bv.y, bv.z, bv.w};
    #pragma unroll
    for (int j = 0; j < 4; j++) { FMA8(acc[j], wa, wb, bvv[j]); }
  }
  #pragma unroll
  for (int j = 0; j < 4; j++)
    #pragma unroll
    for (int i = 0; i < 8; i++)
      hT[c0 + i][bb0 + j] = act_silu(acc[j][i] * 0.125f);
  __syncthreads();

  float acc2[4][8];
  #pragma unroll
  for (int j = 0; j < 4; j++)
    #pragma unroll
    for (int i = 0; i < 8; i++) acc2[j][i] = 0.f;

  for (int k = 0; k < 256; k++) {
    float4 bv = *(const float4*)&hT[k][bb0];
    float4 wa = *(const float4*)&w2[k * 256 + c0];
    float4 wb = *(const float4*)&w2[k * 256 + c0 + 4];
    const float bvv[4] = {bv.x, bv.y, bv.z, bv.w};
    #pragma unroll
    for (int j = 0; j < 4; j++) { FMA8(acc2[j], wa, wb, bvv[j]); }
  }
  __syncthreads();
  #pragma unroll
  for (int j = 0; j < 4; j++)
    #pragma unroll
    for (int i = 0; i < 8; i++)
      hT[c0 + i][bb0 + j] = act_silu(acc2[j][i] * 0.0625f);
  __syncthreads();

  const int jj  = tid & 31;
  const int blg = tid >> 5;
  float acc3[4] = {0.f, 0.f, 0.f, 0.f};
  for (int k = 0; k < 256; k++) {
    float wv  = w3[k * 32 + jj];
    float4 hv = *(const float4*)&hT[k][blg * 4];
    acc3[0] = fmaf(hv.x, wv, acc3[0]);
    acc3[1] = fmaf(hv.y, wv, acc3[1]);
    acc3[2] = fmaf(hv.z, wv, acc3[2]);
    acc3[3] = fmaf(hv.w, wv, acc3[3]);
  }
  const float thrv = gthr[jj];
  #pragma unroll
  for (int r = 0; r < 4; r++) {
    int bl = blg * 4 + r;
    int b  = b0 + bl;
    float rel = acc3[r] * 0.0625f;
    const float* tp = t2s + (size_t)(b * 32 + jj) * 5;
    float tv0 = tp[0], tv1 = tp[1], tv2 = tp[2], tv3 = tp[3], tv4 = tp[4];
    float mag  = sqrtf(tv0*tv0 + tv1*tv1 + tv2*tv2 + tv3*tv3 + tv4*tv4);
    float gate = mag / (mag + thrv);
    float w = rel * gate * 0.17677669529663687f;  // 1/sqrt(32)
    float pm0 = w*tv0, pm1 = w*tv1, pm2 = w*tv2, pm3 = w*tv3, pm4 = w*tv4;
    #pragma unroll
    for (int off = 16; off >= 1; off >>= 1) {
      pm0 += __shfl_xor(pm0, off);
      pm1 += __shfl_xor(pm1, off);
      pm2 += __shfl_xor(pm2, off);
      pm3 += __shfl_xor(pm3, off);
      pm4 += __shfl_xor(pm4, off);
    }
    if (jj == 0) {
      float* mp = mixed_ws + (size_t)b * 5;
      mp[0] = pm0; mp[1] = pm1; mp[2] = pm2; mp[3] = pm3; mp[4] = pm4;
    }
  }
}

// ---------------------------------------------------------------------------
// K2: weight prep.
//  blk [0,64)    : Wsym packed bf16 hi/lo for k_y0 (chunk-major, proven r10)
//  blk [64,128)  : transpose tp2_w202 -> w202T
//  blk [128,205) : B2 pack for k_y2: chunk c=blk-128 in [0,77), off=c*4096+e,
//                  e = w*32 + kk.
//    c in [0,32) : 022, v=c>>1 (0..15), u=(c&1)*32+kk
//    c in [32,64): 202, u=(c-32)>>1,    v=((c-32)&1)*32+kk
//    c in [64,72): 222, K=(c-64)*32+kk, u=K>>4, v=K&15
//    c in [72,77): 220 symmetrized pairs, q=(c-72)*32+kk (valid q<136)
// ---------------------------------------------------------------------------
__global__ __launch_bounds__(256) void k_wprep(
    const float* __restrict__ w000, short* __restrict__ Wh, short* __restrict__ Wl,
    const float* __restrict__ w2202, float* __restrict__ w202T,
    const float* __restrict__ w022, const float* __restrict__ w202,
    const float* __restrict__ w222, const float* __restrict__ w220,
    short* __restrict__ B2h, short* __restrict__ B2l)
{
  const int tid = threadIdx.x;
  const int blk = blockIdx.x;
  if (blk < 64) {
    int u = blk;
    int base = u * 64 - (u * (u - 1)) / 2;
    int n = (64 - u) * 128;
    for (int idx = tid; idx < n; idx += 256) {
      int t = idx >> 7, wc = idx & 127;
      int v = u + t;
      int p = base + t;
      float val = w000[(size_t)(u * 64 + v) * 128 + wc];
      if (v > u) val += w000[(size_t)(v * 64 + u) * 128 + wc];
      int off = ((p >> 5) * 128 + wc) * 32 + (p & 31);
      short hs = f2bf(val);
      Wh[off] = hs;
      Wl[off] = f2bf(val - bf2f(hs));
    }
  } else if (blk < 128) {
    int idx = (blk - 64) * 256 + tid;  // 16384
    int u = idx >> 7, v = idx & 127;
    w202T[v * 128 + u] = w2202[u * 128 + v];
  } else {
    int c = blk - 128;                 // 0..76
    #pragma unroll
    for (int i = 0; i < 16; i++) {
      int e = i * 256 + tid;           // 0..4095
      int w = e >> 5, kk = e & 31;
      float V = 0.f;
      if (c < 32) {
        int v = c >> 1, u = (c & 1) * 32 + kk;
        V = w022[(size_t)(u * 16 + v) * 128 + w];
      } else if (c < 64) {
        int r = c - 32;
        int u = r >> 1, v = (r & 1) * 32 + kk;
        V = w202[(size_t)(u * 64 + v) * 128 + w];
      } else if (c < 72) {
        int K = (c - 64) * 32 + kk;
        int u = K >> 4, v = K & 15;
        V = w222[(size_t)(u * 16 + v) * 128 + w];
      } else {
        int q = (c - 72) * 32 + kk;
        if (q < 136) {
          int u = 0;
          while ((u + 1) * 16 - ((u + 1) * u) / 2 <= q) u++;
          int base = u * 16 - (u * (u - 1)) / 2;
          int v = u + (q - base);
          V = w220[(size_t)(u * 16 + v) * 128 + w];
          if (v > u) V += w220[(size_t)(v * 16 + u) * 128 + w];
        }
      }
      short hs = f2bf(V);
      B2h[(size_t)c * 4096 + e] = hs;
      B2l[(size_t)c * 4096 + e] = f2bf(V - bf2f(hs));
    }
  }
}

// ---------------------------------------------------------------------------
// K_y0: MFMA GEMM for y000 (proven r10, unchanged).
// ---------------------------------------------------------------------------
__global__ __launch_bounds__(256) void k_y0(
    const float* __restrict__ s,
    const short* __restrict__ Wh, const short* __restrict__ Wl,
    float* __restrict__ y0w)
{
  __shared__ float sL[64][64];
  __shared__ unsigned short p16[2080];
  __shared__ __align__(16) short AhL[2048];
  __shared__ __align__(16) short AlL[2048];
  __shared__ __align__(16) short BhL[4096];
  __shared__ __align__(16) short BlL[4096];

  const int tid  = threadIdx.x;
  const int b0   = blockIdx.x * 64;
  const int wave = tid >> 6;
  const int lane = tid & 63;
  const int m16  = lane & 15;
  const int quad = lane >> 4;

  for (int idx = tid; idx < 4096; idx += 256) {
    int bl = idx >> 6, k = idx & 63;
    sL[bl][k] = s[(size_t)(b0 + bl) * 64 + k];
  }
  if (tid < 64) {
    int u = tid;
    int base = u * 64 - (u * (u - 1)) / 2;
    for (int t = 0; t < 64 - u; t++)
      p16[base + t] = (unsigned short)((u << 8) | (u + t));
  }
  __syncthreads();

  f32x4 acc[8];
  #pragma unroll
  for (int nb = 0; nb < 8; nb++) acc[nb] = 0.f;

  for (int c = 0; c < 65; c++) {
    #pragma unroll
    for (int i = 0; i < 8; i++) {
      int e = tid + i * 256;
      int bl = e >> 5, kk = e & 31;
      int uv = p16[c * 32 + kk];
      float x = sL[bl][uv >> 8] * sL[bl][uv & 255];
      short hs = f2bf(x);
      AhL[e] = hs;
      AlL[e] = f2bf(x - bf2f(hs));
    }
    {
      const short8* gh = (const short8*)(Wh + (size_t)c * 4096);
      const short8* gl = (const short8*)(Wl + (size_t)c * 4096);
      ((short8*)BhL)[tid]       = gh[tid];
      ((short8*)BhL)[tid + 256] = gh[tid + 256];
      ((short8*)BlL)[tid]       = gl[tid];
      ((short8*)BlL)[tid + 256] = gl[tid + 256];
    }
    __syncthreads();

    short8 ah = *(const short8*)&AhL[(wave * 16 + m16) * 32 + quad * 8];
    short8 al = *(const short8*)&AlL[(wave * 16 + m16) * 32 + quad * 8];
    #pragma unroll
    for (int nb = 0; nb < 8; nb++) {
      short8 bh = *(const short8*)&BhL[(nb * 16 + m16) * 32 + quad * 8];
      short8 bl = *(const short8*)&BlL[(nb * 16 + m16) * 32 + quad * 8];
      acc[nb] = __builtin_amdgcn_mfma_f32_16x16x32_bf16(ah, bh, acc[nb], 0, 0, 0);
      acc[nb] = __builtin_amdgcn_mfma_f32_16x16x32_bf16(ah, bl, acc[nb], 0, 0, 0);
      acc[nb] = __builtin_amdgcn_mfma_f32_16x16x32_bf16(al, bh, acc[nb], 0, 0, 0);
    }
    __syncthreads();
  }

  #pragma unroll
  for (int nb = 0; nb < 8; nb++) {
    #pragma unroll
    for (int r = 0; r < 4; r++) {
      int b  = b0 + wave * 16 + quad * 4 + r;
      int ch = nb * 16 + m16;
      y0w[(size_t)b * 128 + ch] = acc[nb][r];
    }
  }
}

// ---------------------------------------------------------------------------
// K_y2: MFMA GEMM for tp022+tp202+tp222+y220. 256 blocks x 512 thr (8 waves).
// Block: 64 b. Wave -> (bg = wave&3 -> 16 b, nh = wave>>2 -> 64 channels).
// A built per-lane in registers; B double-buffered in LDS; 3-MFMA split-bf16.
// ---------------------------------------------------------------------------
__global__ __launch_bounds__(512) void k_y2(
    const float* __restrict__ s, const float* __restrict__ t2s,
    const short* __restrict__ B2h, const short* __restrict__ B2l,
    float* __restrict__ y0w, unsigned short* __restrict__ y2p, Coefs cf)
{
  __shared__ float sL[64][68];                 // 17408 B
  __shared__ float tL[64][81];                 // 20736 B ([b][u*5+m])
  __shared__ __align__(16) short BhL[2][4096]; // 16384 B
  __shared__ __align__(16) short BlL[2][4096]; // 16384 B
  __shared__ float cL222[125];
  __shared__ unsigned char p136s[136];
  // ~71.5 KB

  const int tid  = threadIdx.x;
  const int b0   = blockIdx.x * 64;
  const int wave = tid >> 6;
  const int lane = tid & 63;
  const int m16  = lane & 15;
  const int quad = lane >> 4;
  const int bg   = wave & 3;
  const int nh   = wave >> 2;
  const int bloc = bg * 16 + m16;      // A-row (m) batch-local
  const int wbase = nh * 64;

  float dk022[5], dk202[5], dk220[5];
  #pragma unroll
  for (int k = 0; k < 5; k++) {
    dk022[k] = cf.d022[k]; dk202[k] = cf.d202[k]; dk220[k] = cf.d220[k];
  }

  // ---- stage s, t, c222, pair table ----
  if (tid == 0) {
    #pragma unroll
    for (int i = 0; i < 125; i++) cL222[i] = cf.c222[i];
  }
  for (int idx = tid; idx < 4096; idx += 512) {
    int bl = idx >> 6, k = idx & 63;
    sL[bl][k] = s[(size_t)(b0 + bl) * 64 + k];
  }
  for (int idx = tid; idx < 5120; idx += 512) {
    int bl = idx / 80, rem = idx - bl * 80;
    int u = rem / 5, m = rem - u * 5;
    int b = b0 + bl;
    float v;
    if (u < 15) v = t2s[(size_t)(b * 32 + u) * 5 + m];
    else {
      v = 0.f;
      for (int kk = 0; kk < 32; kk++) v += t2s[(size_t)(b * 32 + kk) * 5 + m];
    }
    tL[bl][rem] = v;     // rem == u*5+m
  }
  if (tid < 16) {
    int u = tid;
    int base = u * 16 - (u * (u - 1)) / 2;
    for (int t = 0; t < 16 - u; t++)
      p136s[base + t] = (unsigned char)((u << 4) | (u + t));
  }
  __syncthreads();

  // preload chunk 0
  ((short8*)BhL[0])[tid] = ((const short8*)B2h)[tid];
  ((short8*)BlL[0])[tid] = ((const short8*)B2l)[tid];
  __syncthreads();

  f32x4 acc[5][4];
  #pragma unroll
  for (int k = 0; k < 5; k++)
    #pragma unroll
    for (int nf = 0; nf < 4; nf++) acc[k][nf] = 0.f;
  f32x4 accY0[4];
  #pragma unroll
  for (int nf = 0; nf < 4; nf++) accY0[nf] = 0.f;

  for (int c = 0; c < NCHUNK2; c++) {
    const int cur = c & 1;
    if (c + 1 < NCHUNK2) {
      ((short8*)BhL[cur ^ 1])[tid] = ((const short8*)(B2h + (size_t)(c + 1) * 4096))[tid];
      ((short8*)BlL[cur ^ 1])[tid] = ((const short8*)(B2l + (size_t)(c + 1) * 4096))[tid];
    }
    // B fragments for this chunk (k-independent)
    short8 bhv[4], blv[4];
    #pragma unroll
    for (int nf = 0; nf < 4; nf++) {
      int w = wbase + nf * 16 + m16;
      bhv[nf] = *(const short8*)&BhL[cur][w * 32 + quad * 8];
      blv[nf] = *(const short8*)&BlL[cur][w * 32 + quad * 8];
    }

    if (c < 64) {
      // ---- 022 (c<32) / 202 (c in [32,64)): A_k = f_k * s-slice ----
      int v_or_u, s0;
      const float* dk;
      if (c < 32) { v_or_u = c >> 1; s0 = (c & 1) * 32; dk = dk022; }
      else        { int r = c - 32; v_or_u = r >> 1; s0 = (r & 1) * 32; dk = dk202; }
      float sv[8];
      {
        float4 a = *(const float4*)&sL[bloc][s0 + quad * 8];
        float4 b = *(const float4*)&sL[bloc][s0 + quad * 8 + 4];
        sv[0]=a.x; sv[1]=a.y; sv[2]=a.z; sv[3]=a.w;
        sv[4]=b.x; sv[5]=b.y; sv[6]=b.z; sv[7]=b.w;
      }
      #pragma unroll
      for (int k = 0; k < 5; k++) {
        float f = dk[k] * tL[bloc][v_or_u * 5 + k];
        short8 ah, al;
        #pragma unroll
        for (int j = 0; j < 8; j++) {
          float x = f * sv[j];
          short hs = f2bf(x);
          ah[j] = hs;
          al[j] = f2bf(x - bf2f(hs));
        }
        #pragma unroll
        for (int nf = 0; nf < 4; nf++) {
          acc[k][nf] = __builtin_amdgcn_mfma_f32_16x16x32_bf16(ah, bhv[nf], acc[k][nf], 0, 0, 0);
          acc[k][nf] = __builtin_amdgcn_mfma_f32_16x16x32_bf16(ah, blv[nf], acc[k][nf], 0, 0, 0);
          acc[k][nf] = __builtin_amdgcn_mfma_f32_16x16x32_bf16(al, bhv[nf], acc[k][nf], 0, 0, 0);
        }
      }
    } else if (c < 72) {
      // ---- 222 segment: A_k = Q[b][u][v][k] built in-lane ----
      int cc = c - 64;
      int u  = cc * 2 + (quad >> 1);
      int vb = (quad & 1) * 8;
      float tu[5];
      #pragma unroll
      for (int i = 0; i < 5; i++) tu[i] = tL[bloc][u * 5 + i];
      float G[25];
      #pragma unroll
      for (int jk = 0; jk < 25; jk++) {
        float g = 0.f;
        #pragma unroll
        for (int i = 0; i < 5; i++)
          g = fmaf(cL222[i * 25 + jk], tu[i], g);
        G[jk] = g;
      }
      float av[5][8];
      #pragma unroll
      for (int j = 0; j < 8; j++) {
        float t5[5];
        #pragma unroll
        for (int j5 = 0; j5 < 5; j5++) t5[j5] = tL[bloc][(vb + j) * 5 + j5];
        #pragma unroll
        for (int k = 0; k < 5; k++) {
          float q = 0.f;
          #pragma unroll
          for (int j5 = 0; j5 < 5; j5++)
            q = fmaf(G[j5 * 5 + k], t5[j5], q);
          av[k][j] = q;
        }
      }
      #pragma unroll
      for (int k = 0; k < 5; k++) {
        short8 ah, al;
        #pragma unroll
        for (int j = 0; j < 8; j++) {
          float x = av[k][j];
          short hs = f2bf(x);
          ah[j] = hs;
          al[j] = f2bf(x - bf2f(hs));
        }
        #pragma unroll
        for (int nf = 0; nf < 4; nf++) {
          acc[k][nf] = __builtin_amdgcn_mfma_f32_16x16x32_bf16(ah, bhv[nf], acc[k][nf], 0, 0, 0);
          acc[k][nf] = __builtin_amdgcn_mfma_f32_16x16x32_bf16(ah, blv[nf], acc[k][nf], 0, 0, 0);
          acc[k][nf] = __builtin_amdgcn_mfma_f32_16x16x32_bf16(al, bhv[nf], acc[k][nf], 0, 0, 0);
        }
      }
    } else {
      // ---- 220 segment: A = gram (no k), accumulate into accY0 ----
      int cc = c - 72;
      int qbase = cc * 32 + quad * 8;
      short8 ah, al;
      #pragma unroll
      for (int j = 0; j < 8; j++) {
        int q = qbase + j;
        float g = 0.f;
        if (q < 136) {
          int uv = p136s[q];
          int u = uv >> 4, v = uv & 15;
          #pragma unroll
          for (int m = 0; m < 5; m++)
            g = fmaf(dk220[m] * tL[bloc][u * 5 + m], tL[bloc][v * 5 + m], g);
        }
        short hs = f2bf(g);
        ah[j] = hs;
        al[j] = f2bf(g - bf2f(hs));
      }
      #pragma unroll
      for (int nf = 0; nf < 4; nf++) {
        accY0[nf] = __builtin_amdgcn_mfma_f32_16x16x32_bf16(ah, bhv[nf], accY0[nf], 0, 0, 0);
        accY0[nf] = __builtin_amdgcn_mfma_f32_16x16x32_bf16(ah, blv[nf], accY0[nf], 0, 0, 0);
        accY0[nf] = __builtin_amdgcn_mfma_f32_16x16x32_bf16(al, bhv[nf], accY0[nf], 0, 0, 0);
      }
    }
    __syncthreads();   // frag reads done AND next-chunk staging complete
  }

  // ---- epilogue: D row = quad*4+r (b-local in bg), col = m16 (ch-local) ----
  #pragma unroll
  for (int nf = 0; nf < 4; nf++) {
    int ch = wbase + nf * 16 + m16;
    #pragma unroll
    for (int r = 0; r < 4; r++) {
      int b = b0 + bg * 16 + quad * 4 + r;
      #pragma unroll
      for (int k = 0; k < 5; k++)
        y2p[((size_t)b * 5 + k) * 128 + ch] = (unsigned short)f2bf(acc[k][nf][r]);
      y0w[(size_t)b * 128 + ch] += accY0[nf][r];
    }
  }
}

// ---------------------------------------------------------------------------
// K_fused: y0/y2 load + phase5 + epilogue. 32 b per block, 512 blocks,
// 512 threads, ~37 KB LDS. Phase5 copied from proven r9.
// ---------------------------------------------------------------------------
__global__ __launch_bounds__(512) void k_fused(
    const float* __restrict__ mixed_ws,
    const float* __restrict__ y0w, const unsigned short* __restrict__ y2p,
    const float* __restrict__ w2022, const float* __restrict__ w202T,
    const float* __restrict__ w2222,
    const float* __restrict__ csc, float* __restrict__ out, Coefs cf)
{
  __shared__ __align__(16) float y0I[16][128][2];  // 16384 B
  __shared__ float cL222[125];
  __shared__ float corrAcc[32][5];
  __shared__ float pPL[32][25];
  __shared__ __align__(16) float y2iI[16][128][2]; // 16384 B

  const int tid = threadIdx.x;
  const int b0  = blockIdx.x * 32;

  float dk022[5], dk202[5];
  #pragma unroll
  for (int k = 0; k < 5; k++) { dk022[k] = cf.d022[k]; dk202[k] = cf.d202[k]; }

  if (tid == 0) {
    #pragma unroll
    for (int i = 0; i < 125; i++) cL222[i] = cf.c222[i];
  }
  // stage y0 (a0-scaled) in interleaved-pair layout
  for (int idx = tid; idx < 4096; idx += 512) {
    int bl = idx >> 7, ch = idx & 127;
    y0I[bl >> 1][ch][bl & 1] = cf.a0 * y0w[(size_t)(b0 + bl) * 128 + ch];
  }
  __syncthreads();

  const int xw = tid & 31;
  const int g  = tid >> 5;
  const int w0 = xw * 4;
  const int bA = 2 * g, bB = 2 * g + 1;

  // y2 fragments from ws (bf16), a2-scaled
  float y2acc[5][2][4];
  #pragma unroll
  for (int k = 0; k < 5; k++) {
    #pragma unroll
    for (int h = 0; h < 2; h++) {
      int b = b0 + 2 * g + h;
      const unsigned short* yp = y2p + ((size_t)b * 5 + k) * 128 + w0;
      ushort4 u4 = *(const ushort4*)yp;
      y2acc[k][h][0] = cf.a2 * bf2f((short)u4.x);
      y2acc[k][h][1] = cf.a2 * bf2f((short)u4.y);
      y2acc[k][h][2] = cf.a2 * bf2f((short)u4.z);
      y2acc[k][h][3] = cf.a2 * bf2f((short)u4.w);
    }
  }

  // ================= phase 5 (proven r9 code) =================
  // 022 path
  {
    float gvr[2][4] = {{0.f,0.f,0.f,0.f},{0.f,0.f,0.f,0.f}};
    #pragma unroll 8
    for (int u = 0; u < 128; u++) {
      float2 y0p = *(const float2*)&y0I[g][u][0];
      float4 w4 = *(const float4*)(w2022 + (size_t)u * 128 + w0);
      FMA4(gvr[0], w4, y0p.x);
      FMA4(gvr[1], w4, y0p.y);
    }
    #pragma unroll
    for (int k = 0; k < 5; k++) {
      float pA = gvr[0][0]*y2acc[k][0][0] + gvr[0][1]*y2acc[k][0][1]
               + gvr[0][2]*y2acc[k][0][2] + gvr[0][3]*y2acc[k][0][3];
      float pB = gvr[1][0]*y2acc[k][1][0] + gvr[1][1]*y2acc[k][1][1]
               + gvr[1][2]*y2acc[k][1][2] + gvr[1][3]*y2acc[k][1][3];
      pA += __shfl_xor(pA, 16); pA += __shfl_xor(pA, 8); pA += __shfl_xor(pA, 4);
      pA += __shfl_xor(pA, 2);  pA += __shfl_xor(pA, 1);
      pB += __shfl_xor(pB, 16); pB += __shfl_xor(pB, 8); pB += __shfl_xor(pB, 4);
      pB += __shfl_xor(pB, 2);  pB += __shfl_xor(pB, 1);
      if (xw == 0) {
        corrAcc[bA][k] = dk022[k] * pA;
        corrAcc[bB][k] = dk022[k] * pB;
      }
    }
  }
  // 202 path
  {
    float hvr[2][4] = {{0.f,0.f,0.f,0.f},{0.f,0.f,0.f,0.f}};
    #pragma unroll 8
    for (int v = 0; v < 128; v++) {
      float2 y0p = *(const float2*)&y0I[g][v][0];
      float4 w4 = *(const float4*)(w202T + (size_t)v * 128 + w0);
      FMA4(hvr[0], w4, y0p.x);
      FMA4(hvr[1], w4, y0p.y);
    }
    #pragma unroll
    for (int k = 0; k < 5; k++) {
      float pA = hvr[0][0]*y2acc[k][0][0] + hvr[0][1]*y2acc[k][0][1]
               + hvr[0][2]*y2acc[k][0][2] + hvr[0][3]*y2acc[k][0][3];
      float pB = hvr[1][0]*y2acc[k][1][0] + hvr[1][1]*y2acc[k][1][1]
               + hvr[1][2]*y2acc[k][1][2] + hvr[1][3]*y2acc[k][1][3];
      pA += __shfl_xor(pA, 16); pA += __shfl_xor(pA, 8); pA += __shfl_xor(pA, 4);
      pA += __shfl_xor(pA, 2);  pA += __shfl_xor(pA, 1);
      pB += __shfl_xor(pB, 16); pB += __shfl_xor(pB, 8); pB += __shfl_xor(pB, 4);
      pB += __shfl_xor(pB, 2);  pB += __shfl_xor(pB, 1);
      if (xw == 0) {
        corrAcc[bA][k] += dk202[k] * pA;
        corrAcc[bB][k] += dk202[k] * pB;
      }
    }
  }
  // 222 path
  for (int i = 0; i < 5; i++) {
    #pragma unroll
    for (int wi = 0; wi < 4; wi++) {
      float2 o; o.x = y2acc[i][0][wi]; o.y = y2acc[i][1][wi];
      *(float2*)&y2iI[g][w0 + wi][0] = o;
    }
    __syncthreads();
    float zr[2][4] = {{0.f,0.f,0.f,0.f},{0.f,0.f,0.f,0.f}};
    #pragma unroll 8
    for (int u = 0; u < 128; u++) {
      float2 yp = *(const float2*)&y2iI[g][u][0];
      float4 w4 = *(const float4*)(w2222 + (size_t)u * 128 + w0);
      FMA4(zr[0], w4, yp.x);
      FMA4(zr[1], w4, yp.y);
    }
    #pragma unroll
    for (int j = 0; j < 5; j++) {
      float pA = zr[0][0]*y2acc[j][0][0] + zr[0][1]*y2acc[j][0][1]
               + zr[0][2]*y2acc[j][0][2] + zr[0][3]*y2acc[j][0][3];
      float pB = zr[1][0]*y2acc[j][1][0] + zr[1][1]*y2acc[j][1][1]
               + zr[1][2]*y2acc[j][1][2] + zr[1][3]*y2acc[j][1][3];
      pA += __shfl_xor(pA, 16); pA += __shfl_xor(pA, 8); pA += __shfl_xor(pA, 4);
      pA += __shfl_xor(pA, 2);  pA += __shfl_xor(pA, 1);
      pB += __shfl_xor(pB, 16); pB += __shfl_xor(pB, 8); pB += __shfl_xor(pB, 4);
      pB += __shfl_xor(pB, 2);  pB += __shfl_xor(pB, 1);
      if (xw == 0) {
        pPL[bA][i * 5 + j] = pA;
        pPL[bB][i * 5 + j] = pB;
      }
    }
    __syncthreads();
  }

  // ---- epilogue ----
  if (tid < 160) {
    int bb = tid / 5, k = tid - bb * 5;
    float c2 = 0.f;
    #pragma unroll
    for (int ii = 0; ii < 5; ii++)
      #pragma unroll
      for (int jj = 0; jj < 5; jj++)
        c2 = fmaf(cL222[ii * 25 + jj * 5 + k], pPL[bb][ii * 5 + jj], c2);
    float tot = corrAcc[bb][k] + c2;
    int b = b0 + bb;
    out[(size_t)b * 5 + k] = mixed_ws[(size_t)b * 5 + k] + csc[0] * cf.b2 * tot;
  }
}

// ---------------------------------------------------------------------------
// Host: replicate reference's wigner-3j computation (RREF null space).
// ---------------------------------------------------------------------------
namespace {

using cplx = std::complex<double>;

static void su2_gen(int l, std::vector<cplx>& Jx, std::vector<cplx>& Jy,
                    std::vector<cplx>& Jz) {
  int d = 2 * l + 1;
  Jx.assign((size_t)d * d, cplx(0, 0));
  Jy.assign((size_t)d * d, cplx(0, 0));
  Jz.assign((size_t)d * d, cplx(0, 0));
  for (int a = 0; a < d; a++) Jz[(size_t)a * d + a] = cplx(a - l, 0);
  for (int r = 1; r < d; r++) {
    double m = (r - 1) - l;
    double v = std::sqrt(l * (l + 1.0) - m * (m + 1.0));
    Jx[(size_t)r * d + (r - 1)] += cplx(v / 2, 0);
    Jx[(size_t)(r - 1) * d + r] += cplx(v / 2, 0);
    Jy[(size_t)r * d + (r - 1)] += cplx(0, -v / 2);
    Jy[(size_t)(r - 1) * d + r] += cplx(0, v / 2);
  }
}

static void real_basis(int l, std::vector<cplx>& U) {
  int d = 2 * l + 1;
  U.assign((size_t)d * d, cplx(0, 0));
  U[(size_t)l * d + l] = cplx(1, 0);
  double is2 = 1.0 / std::sqrt(2.0);
  for (int m = 1; m <= l; m++) {
    double sgn = (m % 2 == 0) ? 1.0 : -1.0;
    U[(size_t)(l + m) * d + (l + m)] = cplx(sgn * is2, 0);
    U[(size_t)(l + m) * d + (l - m)] = cplx(is2, 0);
    U[(size_t)(l - m) * d + (l - m)] = cplx(0, is2);
    U[(size_t)(l - m) * d + (l + m)] = cplx(0, -sgn * is2);
  }
}

static void real_gens(int l, std::vector<double> G[3]) {
  int d = 2 * l + 1;
  if (l == 0) { for (int a = 0; a < 3; a++) G[a].assign(1, 0.0); return; }
  std::vector<cplx> J[3];
  su2_gen(l, J[0], J[1], J[2]);
  std::vector<cplx> U;
  real_basis(l, U);
  for (int a = 0; a < 3; a++) {
    std::vector<cplx> T((size_t)d * d, cplx(0, 0));
    for (int i = 0; i < d; i++)
      for (int k = 0; k < d; k++) {
        cplx s(0, 0);
        for (int j = 0; j < d; j++)
          s += U[(size_t)i * d + j] * (cplx(0, -1) * J[a][(size_t)j * d + k]);
        T[(size_t)i * d + k] = s;
      }
    G[a].assign((size_t)d * d, 0.0);
    for (int i = 0; i < d; i++)
      for (int k = 0; k < d; k++) {
        cplx s(0, 0);
        for (int j = 0; j < d; j++)
          s += T[(size_t)i * d + j] * std::conj(U[(size_t)k * d + j]);
        G[a][(size_t)i * d + k] = s.real();
      }
  }
}

static void w3j_host(int l1, int l2, int l3, float* out) {
  int d1 = 2 * l1 + 1, d2 = 2 * l2 + 1, d3 = 2 * l3 + 1;
  int D = d1 * d2 * d3;
  std::vector<double> G1[3], G2[3], G3[3];
  real_gens(l1, G1); real_gens(l2, G2); real_gens(l3, G3);
  int R = 3 * D;
  std::vector<double> M((size_t)R * D, 0.0);
  for (int a = 0; a < 3; a++) {
    double* Ma = &M[(size_t)a * D * D];
    for (int i1 = 0; i1 < d1; i1++)
      for (int j1 = 0; j1 < d1; j1++) {
        double g = G1[a][(size_t)i1 * d1 + j1];
        if (g == 0.0) continue;
        for (int i2 = 0; i2 < d2; i2++)
          for (int i3 = 0; i3 < d3; i3++)
            Ma[(size_t)((i1 * d2 + i2) * d3 + i3) * D + ((j1 * d2 + i2) * d3 + i3)] += g;
      }
    for (int i2 = 0; i2 < d2; i2++)
      for (int j2 = 0; j2 < d2; j2++) {
        double g = G2[a][(size_t)i2 * d2 + j2];
        if (g == 0.0) continue;
        for (int i1 = 0; i1 < d1; i1++)
          for (int i3 = 0; i3 < d3; i3++)
            Ma[(size_t)((i1 * d2 + i2) * d3 + i3) * D + ((i1 * d2 + j2) * d3 + i3)] += g;
      }
    for (int i3 = 0; i3 < d3; i3++)
      for (int j3 = 0; j3 < d3; j3++) {
        double g = G3[a][(size_t)i3 * d3 + j3];
        if (g == 0.0) continue;
        for (int i1 = 0; i1 < d1; i1++)
          for (int i2 = 0; i2 < d2; i2++)
            Ma[(size_t)((i1 * d2 + i2) * d3 + i3) * D + ((i1 * d2 + i2) * d3 + j3)] += g;
      }
  }
  std::vector<int> pivcol;
  int rank = 0;
  for (int col = 0; col < D && rank < R; col++) {
    int pr = -1; double pv = 1e-9;
    for (int r = rank; r < R; r++) {
      double av = std::fabs(M[(size_t)r * D + col]);
      if (av > pv) { pv = av; pr = r; }
    }
    if (pr < 0) continue;
    if (pr != rank)
      for (int c = 0; c < D; c++) std::swap(M[(size_t)pr * D + c], M[(size_t)rank * D + c]);
    double inv = 1.0 / M[(size_t)rank * D + col];
    for (int c = 0; c < D; c++) M[(size_t)rank * D + c] *= inv;
    for (int r = 0; r < R; r++) {
      if (r == rank) continue;
      double f = M[(size_t)r * D + col];
      if (f != 0.0)
        for (int c = 0; c < D; c++) M[(size_t)r * D + c] -= f * M[(size_t)rank * D + c];
    }
    pivcol.push_back(col);
    rank++;
  }
  std::vector<char> isp(D, 0);
  for (int c : pivcol) isp[c] = 1;
  int fc = 0;
  for (int c = 0; c < D; c++) if (!isp[c]) { fc = c; break; }
  std::vector<double> x(D, 0.0);
  x[fc] = 1.0;
  for (int r = 0; r < rank; r++) x[pivcol[r]] = -M[(size_t)r * D + fc];
  double n = 0;
  for (double v : x) n += v * v;
  n = std::sqrt(n);
  for (int c = 0; c < D; c++) x[c] /= n;
  double best = 0;
  for (int c = 0; c < D; c++) { double av = std::fabs(x[c]); if (av > best) best = av; }
  double ssum = 0;
  for (int c = 0; c < D; c++) {
    double av = std::fabs(x[c]);
    if (av >= best * 0.999) ssum += (x[c] >= 0 ? 1.0 : -1.0);
  }
  double sgn = (ssum >= 0) ? 1.0 : -1.0;
  for (int c = 0; c < D; c++) out[c] = (float)(x[c] * sgn);
}

}  // namespace

// ---------------------------------------------------------------------------
extern "C" void kernel_launch(void* const* d_in, const int* in_sizes, int n_in,
                              void* d_out, int out_size, void* d_ws, size_t ws_size,
                              hipStream_t stream)
{
  (void)in_sizes; (void)n_in; (void)out_size; (void)ws_size;

  const float* s     = (const float*)d_in[0];
  const float* t2s   = (const float*)d_in[1];
  const float* w1    = (const float*)d_in[2];
  const float* w2    = (const float*)d_in[3];
  const float* w3    = (const float*)d_in[4];
  const float* gthr  = (const float*)d_in[5];
  const float* w000  = (const float*)d_in[6];
  const float* w220  = (const float*)d_in[7];
  const float* w022  = (const float*)d_in[8];
  const float* w202  = (const float*)d_in[9];
  const float* w222  = (const float*)d_in[10];
  const float* w2022 = (const float*)d_in[11];
  const float* w2202 = (const float*)d_in[12];
  const float* w2222 = (const float*)d_in[13];
  const float* csc   = (const float*)d_in[14];
  float* out = (float*)d_out;

  char* ws = (char*)d_ws;
  float* mixed_ws = (float*)(ws + MIX_WS_OFF);
  float* w202T    = (float*)(ws + W202T_OFF);
  short* WsymH    = (short*)(ws + WSYMH_OFF);
  short* WsymL    = (short*)(ws + WSYML_OFF);
  short* B2h      = (short*)(ws + B2H_OFF);
  short* B2l      = (short*)(ws + B2L_OFF);
  float* y0_ws    = (float*)(ws + Y0_WS_OFF);
  unsigned short* y2p = (unsigned short*)(ws + Y2P_OFF);

  Coefs cf;
  {
    float c000v[1], c022v[25], c202v[25], c220v[25];
    w3j_host(0, 0, 0, c000v);
    w3j_host(0, 2, 2, c022v);
    w3j_host(2, 0, 2, c202v);
    w3j_host(2, 2, 0, c220v);
    w3j_host(2, 2, 2, cf.c222);
    for (int i = 0; i < 125; i++) cf.c222[i] *= C222_FLIP;
    for (int k = 0; k < 5; k++) {
      cf.d022[k] = c022v[k * 5 + k];
      cf.d202[k] = c202v[k * 5 + k];
      cf.d220[k] = c220v[k * 5 + k];
    }
    (void)c000v;
    cf.a0 = (float)std::sqrt(1.0 / (64.0 * 64.0 + 16.0 * 16.0));
    cf.a2 = (float)std::sqrt(5.0 / (2.0 * 64.0 * 16.0 + 16.0 * 16.0));
    cf.b2 = (float)std::sqrt(5.0 / (3.0 * 128.0 * 128.0));
  }

  hipLaunchKernelGGL(k_prep, dim3(512), dim3(256), 0, stream,
                     s, t2s, w1, w2, w3, gthr, mixed_ws);
  hipLaunchKernelGGL(k_wprep, dim3(205), dim3(256), 0, stream,
                     w000, WsymH, WsymL, w2202, w202T,
                     w022, w202, w222, w220, B2h, B2l);
  hipLaunchKernelGGL(k_y0, dim3(256), dim3(256), 0, stream,
                     s, WsymH, WsymL, y0_ws);
  hipLaunchKernelGGL(k_y2, dim3(256), dim3(512), 0, stream,
                     s, t2s, B2h, B2l, y0_ws, y2p, cf);
  hipLaunchKernelGGL(k_fused, dim3(512), dim3(512), 0, stream,
                     mixed_ws, y0_ws, y2p, w2022, w202T, w2222, csc, out, cf);
}